// Round 6
// baseline (936.304 us; speedup 1.0000x reference)
//
#include <hip/hip_runtime.h>

typedef unsigned short u16;
typedef unsigned int   u32;

using bf16x8 = __attribute__((ext_vector_type(8))) short;  // 8 bf16 in 4 VGPRs
using f32x4  = __attribute__((ext_vector_type(4))) float;

__device__ __forceinline__ float bf2f(u16 h) {
  u32 u = ((u32)h) << 16;
  return __builtin_bit_cast(float, u);
}
__device__ __forceinline__ u16 f2bf(float f) {   // round-to-nearest-even
  u32 u = __builtin_bit_cast(u32, f);
  u += 0x7fffu + ((u >> 16) & 1u);
  return (u16)(u >> 16);
}

__device__ __forceinline__ void gload16(const u16* src, u16* ldsdst) {
  __builtin_amdgcn_global_load_lds(
      (const __attribute__((address_space(1))) void*)src,
      (__attribute__((address_space(3))) void*)ldsdst, 16, 0, 0);
}

// m204 bijective XCD swizzle
__device__ __forceinline__ int xcd_swz(int wg, int nwg) {
  int q = nwg >> 3, r = nwg & 7, xcd = wg & 7, loc = wg >> 3;
  return (xcd < r ? xcd * (q + 1) : r * (q + 1) + (xcd - r) * q) + loc;
}

// ---------------------------------------------------------------------------
__global__ __launch_bounds__(256) void cvt_bf16(const float* __restrict__ in,
                                                u16* __restrict__ out, int n8) {
  int i = blockIdx.x * 256 + threadIdx.x;
  if (i >= n8) return;
  const float* p = in + (size_t)i * 8;
  bf16x8 o;
#pragma unroll
  for (int j = 0; j < 8; ++j) o[j] = (short)f2bf(p[j]);
  *(bf16x8*)(out + (size_t)i * 8) = o;
}

// ---------------------------------------------------------------------------
__global__ __launch_bounds__(256) void hgen(const float* __restrict__ x,
                                            const float* __restrict__ W,
                                            const float* __restrict__ bias,
                                            u16* __restrict__ h, int F, int logF,
                                            int b0, int xstride, int total8) {
  int idx = blockIdx.x * 256 + threadIdx.x;
  if (idx >= total8) return;
  int d0 = (idx & 127) << 3;
  int m  = idx >> 7;
  int f  = m & (F - 1);
  int b  = b0 + (m >> logF);
  float xv = x[(size_t)b * xstride + f];
  const float* wp = W + (size_t)f * 1024 + d0;
  const float* bp = bias + (size_t)f * 1024 + d0;
  bf16x8 o;
#pragma unroll
  for (int j = 0; j < 8; ++j) o[j] = (short)f2bf(fmaxf(xv * wp[j] + bp[j], 0.f));
  *(bf16x8*)(h + (size_t)m * 1024 + d0) = o;
}

// ---------------------------------------------------------------------------
// C(MxN, bf16) = A(MxK, bf16) * B^T (B stored NxK) + bias(N, f32)
// 256x128 tile, BK=32, 8 waves (4M x 2N), per-wave 64x64.
// TRIPLE-buffered (72 KB LDS -> 2 blocks/CU) with counted vmcnt:
//   tile t: stage(t+2)->buf[(t+2)%3]; ds_read buf[t%3]; lgkmcnt(0); 16 MFMA;
//           vmcnt(3) [keeps t+2's 3 loads in flight]; s_barrier.
// Ledger: outstanding at wait = t+1's 3 + t+2's 3; vmcnt(3) retires t+1's.
// Tail (no stage issued this tile): vmcnt(0).
// Swizzle swz(r) = (r>>1)&3: 16 lanes reading rows base..base+15 hit 8
// distinct bank-quads x2 (2-way = free class, measured 0 conflicts at BK=64).
// Requires M%256==0, N%128==0, K%32==0, K/32>=2.
__global__ __launch_bounds__(512, 4) void gemm_ph(const u16* __restrict__ A,
                                                  const u16* __restrict__ B,
                                                  const float* __restrict__ bias,
                                                  u16* __restrict__ C,
                                                  int M, int N, int K) {
  __shared__ u16 sA[3][256 * 32];   // 3 x 16 KB, chunk = 16 rows x 64 B
  __shared__ u16 sB[3][128 * 32];   // 3 x  8 KB
  const int tid  = threadIdx.x;
  const int lane = tid & 63;
  const int w    = tid >> 6;
  const int wm   = w >> 1;          // 0..3 : 64-row group
  const int wn   = w & 1;           // 0..1 : 64-col group

  const int nwg = gridDim.x * gridDim.y;
  const int wg  = blockIdx.y * gridDim.x + blockIdx.x;
  const int swz = xcd_swz(wg, nwg);
  const int n0 = (swz % gridDim.x) * 128;
  const int m0 = (swz / gridDim.x) * 256;

  f32x4 acc[4][4] = {};

  const int r_in  = lane >> 2;                       // 0..15 row within chunk
  const int s_src = (lane & 3) ^ ((lane >> 3) & 3);  // (l&3) ^ swz(r_in)

  // stage one K-tile: A chunks {w, w+8}, B chunk {w}; 3 gloads/wave
  auto stage = [&](int kt, int b) {
    const int k0 = kt << 5;
    gload16(A + (size_t)(m0 + w * 16 + r_in) * K + k0 + s_src * 8, &sA[b][w * 512]);
    gload16(A + (size_t)(m0 + (w + 8) * 16 + r_in) * K + k0 + s_src * 8, &sA[b][(w + 8) * 512]);
    gload16(B + (size_t)(n0 + w * 16 + r_in) * K + k0 + s_src * 8, &sB[b][w * 512]);
  };

  const int NT = K >> 5;
  stage(0, 0);
  stage(1, 1);
  asm volatile("s_waitcnt vmcnt(3)" ::: "memory");
  __builtin_amdgcn_s_barrier();

  int cur = 0, nx = 2;
  for (int t = 0; t < NT; ++t) {
    const bool more = (t + 2 < NT);
    if (more) stage(t + 2, nx);

    bf16x8 af[4], bg[4];
    const int g = lane >> 4;         // logical 16B k-slot
#pragma unroll
    for (int mf = 0; mf < 4; ++mf) {
      int ra = wm * 64 + mf * 16 + (lane & 15);
      af[mf] = *(const bf16x8*)(&sA[cur][ra * 32 + ((g ^ ((ra >> 1) & 3)) * 8)]);
    }
#pragma unroll
    for (int nf = 0; nf < 4; ++nf) {
      int rb = wn * 64 + nf * 16 + (lane & 15);
      bg[nf] = *(const bf16x8*)(&sB[cur][rb * 32 + ((g ^ ((rb >> 1) & 3)) * 8)]);
    }
    asm volatile("s_waitcnt lgkmcnt(0)" ::: "memory");
    __builtin_amdgcn_sched_barrier(0);
    __builtin_amdgcn_s_setprio(1);
#pragma unroll
    for (int mf = 0; mf < 4; ++mf)
#pragma unroll
      for (int nf = 0; nf < 4; ++nf)
        acc[mf][nf] = __builtin_amdgcn_mfma_f32_16x16x32_bf16(af[mf], bg[nf], acc[mf][nf], 0, 0, 0);
    __builtin_amdgcn_s_setprio(0);
    if (more) asm volatile("s_waitcnt vmcnt(3)" ::: "memory");
    else      asm volatile("s_waitcnt vmcnt(0)" ::: "memory");
    __builtin_amdgcn_s_barrier();
    cur = (cur == 2) ? 0 : cur + 1;
    nx  = (nx  == 2) ? 0 : nx  + 1;
  }

  // epilogue: D layout col = lane&15, row = (lane>>4)*4 + reg
#pragma unroll
  for (int nf = 0; nf < 4; ++nf) {
    int cl = n0 + wn * 64 + nf * 16 + (lane & 15);
    float bsv = bias[cl];
#pragma unroll
    for (int mf = 0; mf < 4; ++mf) {
      int r0 = m0 + wm * 64 + mf * 16 + (lane >> 4) * 4;
#pragma unroll
      for (int reg = 0; reg < 4; ++reg)
        C[(size_t)(r0 + reg) * N + cl] = f2bf(acc[mf][nf][reg] + bsv);
    }
  }
}

// ---------------------------------------------------------------------------
// Fused attention for one (bc, head, 64-row q-block); 1-D grid + XCD swizzle.
// Staging map: row = tid&63, slots = (tid>>6)*4 + i  ->
//   - vT transpose stores hit 64 CONSECUTIVE u16 (conflict-free; was 16-way)
//   - K/V for kb+1 prefetched to regs before compute of kb (T14): the
//     compiler-inserted vmcnt wait lands at next iteration's ds_write, so
//     HBM latency hides under QK/softmax/PV.
__global__ __launch_bounds__(256) void attn(const u16* __restrict__ qkv,
                                            u16* __restrict__ o_out, int F) {
  __shared__ u16 q_lds[64 * 136];   // [64][128+8]
  __shared__ u16 k_lds[64 * 136];
  __shared__ u16 vT[128 * 72];      // [128 d][64+8 kpos]
  __shared__ u16 p_lds[4 * 16 * 72];// per-wave [16 qrow][64+8 kpos]

  const int tid  = threadIdx.x;
  const int lane = tid & 63;
  const int w    = tid >> 6;
  const int rr_  = tid & 63;        // staging row
  const int sw_  = tid >> 6;        // staging slot group

  const int swzb = xcd_swz(blockIdx.x, gridDim.x);
  const int nqb = F >> 6;
  const int qb   = swzb % nqb;
  const int head = (swzb / nqb) & 7;
  const int bc   = swzb / (nqb * 8);

  const size_t rowbase = (size_t)bc * F * 3072;
  const float scale = 0.08838834764831845f;   // 1/sqrt(128)

  bf16x8 kreg[4], vreg[4];
  auto load_kv = [&](int kb) {
    const u16* ks = qkv + rowbase + (size_t)(kb * 64) * 3072 + 1024 + head * 128;
    const u16* vs = ks + 1024;
#pragma unroll
    for (int i = 0; i < 4; ++i) {
      int s = sw_ * 4 + i;
      kreg[i] = *(const bf16x8*)(ks + (size_t)rr_ * 3072 + s * 8);
      vreg[i] = *(const bf16x8*)(vs + (size_t)rr_ * 3072 + s * 8);
    }
  };

  load_kv(0);
  {  // stage q (scaled)
    const u16* qsrc = qkv + rowbase + (size_t)(qb * 64) * 3072 + head * 128;
#pragma unroll
    for (int i = 0; i < 4; ++i) {
      int s = sw_ * 4 + i;
      bf16x8 v = *(const bf16x8*)(qsrc + (size_t)rr_ * 3072 + s * 8);
      bf16x8 o;
#pragma unroll
      for (int j = 0; j < 8; ++j) o[j] = (short)f2bf(bf2f((u16)v[j]) * scale);
      *(bf16x8*)(q_lds + rr_ * 136 + s * 8) = o;
    }
  }

  f32x4 o_acc[8] = {};
  float m_run = -INFINITY, l_run = 0.f;
  const int qr = lane & 15;
  const int g4 = lane >> 4;

  const int nkb = F >> 6;
  for (int kb = 0; kb < nkb; ++kb) {
    __syncthreads();   // prev compute done with k_lds/vT; q staged (kb==0)
#pragma unroll
    for (int i = 0; i < 4; ++i) {
      int s = sw_ * 4 + i;
      *(bf16x8*)(k_lds + rr_ * 136 + s * 8) = kreg[i];
#pragma unroll
      for (int j = 0; j < 8; ++j) vT[(s * 8 + j) * 72 + rr_] = (u16)vreg[i][j];
    }
    __syncthreads();
    if (kb + 1 < nkb) load_kv(kb + 1);   // prefetch next tile into regs

    // S^T (64 kpos x 16 qrows): A = k rows, B = q^T
    f32x4 sa[4] = {};
#pragma unroll
    for (int kk = 0; kk < 4; ++kk) {
      bf16x8 bq = *(const bf16x8*)(q_lds + (w * 16 + qr) * 136 + kk * 32 + 8 * g4);
#pragma unroll
      for (int f = 0; f < 4; ++f) {
        bf16x8 ak = *(const bf16x8*)(k_lds + (f * 16 + qr) * 136 + kk * 32 + 8 * g4);
        sa[f] = __builtin_amdgcn_mfma_f32_16x16x32_bf16(ak, bq, sa[f], 0, 0, 0);
      }
    }

    float tmax = -INFINITY;
#pragma unroll
    for (int f = 0; f < 4; ++f)
#pragma unroll
      for (int rr = 0; rr < 4; ++rr) tmax = fmaxf(tmax, sa[f][rr]);
    tmax = fmaxf(tmax, __shfl_xor(tmax, 16));
    tmax = fmaxf(tmax, __shfl_xor(tmax, 32));
    float mnew  = fmaxf(m_run, tmax);
    float alpha = __expf(m_run - mnew);
    float psum  = 0.f;
#pragma unroll
    for (int f = 0; f < 4; ++f) {
      u16 pp[4];
#pragma unroll
      for (int rr = 0; rr < 4; ++rr) {
        float p = __expf(sa[f][rr] - mnew);
        psum += p;
        pp[rr] = f2bf(p);
      }
      uint2 u;
      u.x = (u32)pp[0] | ((u32)pp[1] << 16);
      u.y = (u32)pp[2] | ((u32)pp[3] << 16);
      *(uint2*)(p_lds + w * 1152 + qr * 72 + f * 16 + g4 * 4) = u;
    }
    psum += __shfl_xor(psum, 16);
    psum += __shfl_xor(psum, 32);
    l_run = l_run * alpha + psum;
    m_run = mnew;

#pragma unroll
    for (int rr = 0; rr < 4; ++rr) {
      float ar = __shfl(alpha, g4 * 4 + rr);
#pragma unroll
      for (int g = 0; g < 8; ++g) o_acc[g][rr] *= ar;
    }

#pragma unroll
    for (int kk2 = 0; kk2 < 2; ++kk2) {
      bf16x8 pa = *(const bf16x8*)(p_lds + w * 1152 + qr * 72 + kk2 * 32 + 8 * g4);
#pragma unroll
      for (int g = 0; g < 8; ++g) {
        bf16x8 vb = *(const bf16x8*)(vT + (g * 16 + qr) * 72 + kk2 * 32 + 8 * g4);
        o_acc[g] = __builtin_amdgcn_mfma_f32_16x16x32_bf16(pa, vb, o_acc[g], 0, 0, 0);
      }
    }
  }

  float linv = 1.f / l_run;
#pragma unroll
  for (int rr = 0; rr < 4; ++rr) {
    float lr = __shfl(linv, g4 * 4 + rr);
    size_t row = (size_t)bc * F + qb * 64 + w * 16 + g4 * 4 + rr;
#pragma unroll
    for (int g = 0; g < 8; ++g)
      o_out[row * 1024 + head * 128 + g * 16 + qr] = f2bf(o_acc[g][rr] * lr);
  }
}

// ---------------------------------------------------------------------------
// Fused LayerNorm: stats (4 waves x 16 rows) + apply/column-sum + atomicAdd.
// One block per 64 rows (all same batch element: 64 | F).
__global__ __launch_bounds__(256) void ln_fused(const u16* __restrict__ proj,
                                                const float* __restrict__ g,
                                                const float* __restrict__ beta,
                                                float* __restrict__ dp, int F, int b0) {
  __shared__ float mu_s[64], rs_s[64];
  const int tid = threadIdx.x, lane = tid & 63, w = tid >> 6;
  const int row0 = blockIdx.x * 64;
  const int b = b0 + row0 / F;

  for (int rr = w * 16; rr < w * 16 + 16; ++rr) {
    const u16* p = proj + (size_t)(row0 + rr) * 1024;
    float s = 0.f, s2 = 0.f;
#pragma unroll
    for (int i = 0; i < 2; ++i) {
      bf16x8 v = *(const bf16x8*)(p + (lane + i * 64) * 8);
#pragma unroll
      for (int j = 0; j < 8; ++j) { float f = bf2f((u16)v[j]); s += f; s2 += f * f; }
    }
#pragma unroll
    for (int m = 1; m < 64; m <<= 1) { s += __shfl_xor(s, m); s2 += __shfl_xor(s2, m); }
    if (lane == 0) {
      float mu  = s * (1.f / 1024.f);
      float var = s2 * (1.f / 1024.f) - mu * mu;
      mu_s[rr] = mu;
      rs_s[rr] = rsqrtf(var + 1e-5f);
    }
  }
  __syncthreads();

  for (int d = tid; d < 1024; d += 256) {
    float acc = 0.f;
    for (int f = 0; f < 64; ++f)
      acc += (bf2f(proj[(size_t)(row0 + f) * 1024 + d]) - mu_s[f]) * rs_s[f];
    atomicAdd(&dp[(size_t)b * 1024 + d], acc * g[d] + 64.f * beta[d]);
  }
}

// ---------------------------------------------------------------------------
__global__ __launch_bounds__(256) void cosine_sig(const float* __restrict__ dp,
                                                  const float* __restrict__ tp,
                                                  float* __restrict__ out) {
  __shared__ float red[3][4];
  int b = blockIdx.x;
  int tid = threadIdx.x, lane = tid & 63, w = tid >> 6;
  float dot = 0.f, n1 = 0.f, n2 = 0.f;
  for (int i = tid; i < 1024; i += 256) {
    float a = dp[(size_t)b * 1024 + i], c = tp[(size_t)b * 1024 + i];
    dot += a * c; n1 += a * a; n2 += c * c;
  }
#pragma unroll
  for (int m = 1; m < 64; m <<= 1) {
    dot += __shfl_xor(dot, m); n1 += __shfl_xor(n1, m); n2 += __shfl_xor(n2, m);
  }
  if (lane == 0) { red[0][w] = dot; red[1][w] = n1; red[2][w] = n2; }
  __syncthreads();
  if (tid == 0) {
    dot = red[0][0] + red[0][1] + red[0][2] + red[0][3];
    n1  = red[1][0] + red[1][1] + red[1][2] + red[1][3];
    n2  = red[2][0] + red[2][1] + red[2][2] + red[2][3];
    float denom = fmaxf(sqrtf(n1) * sqrtf(n2), 1e-8f);
    out[b] = 1.f / (1.f + __expf(-dot / denom));
  }
}

// ---------------------------------------------------------------------------
extern "C" void kernel_launch(void* const* d_in, const int* in_sizes, int n_in,
                              void* d_out, int out_size, void* d_ws, size_t ws_size,
                              hipStream_t stream) {
  const float* drug   = (const float*)d_in[0];
  const float* target = (const float*)d_in[1];

  char* p = (char*)d_ws;
  auto alloc = [&](size_t bytes) -> char* {
    char* r = p; p += (bytes + 255) & ~(size_t)255; return r;
  };

  u16* w_in_d  = (u16*)alloc((size_t)3072 * 1024 * 2);
  u16* w_out_d = (u16*)alloc((size_t)1024 * 1024 * 2);
  u16* w_in_t  = (u16*)alloc((size_t)3072 * 1024 * 2);
  u16* w_out_t = (u16*)alloc((size_t)1024 * 1024 * 2);
  float* dp    = (float*)alloc((size_t)2 * 128 * 1024 * 4);
  float* tp    = dp + 128 * 1024;

  size_t fixed = (size_t)(p - (char*)d_ws);
  size_t per = (size_t)256 * 1024 * 2 * 3
             + (size_t)256 * 3072 * 2
             + (size_t)256 * 8 + 2048;
  int Bc = 8;
  if      (fixed + 128 * per <= ws_size) Bc = 128;
  else if (fixed +  64 * per <= ws_size) Bc = 64;
  else if (fixed +  32 * per <= ws_size) Bc = 32;
  else if (fixed +  16 * per <= ws_size) Bc = 16;

  u16* hbuf    = (u16*)alloc((size_t)Bc * 256 * 1024 * 2);
  u16* qkvbuf  = (u16*)alloc((size_t)Bc * 256 * 3072 * 2);
  u16* obuf    = (u16*)alloc((size_t)Bc * 256 * 1024 * 2);
  u16* projbuf = (u16*)alloc((size_t)Bc * 256 * 1024 * 2);

  cvt_bf16<<<1536, 256, 0, stream>>>((const float*)d_in[4],  w_in_d,  3072 * 128);
  cvt_bf16<<<512,  256, 0, stream>>>((const float*)d_in[6],  w_out_d, 1024 * 128);
  cvt_bf16<<<1536, 256, 0, stream>>>((const float*)d_in[12], w_in_t,  3072 * 128);
  cvt_bf16<<<512,  256, 0, stream>>>((const float*)d_in[14], w_out_t, 1024 * 128);
  hipMemsetAsync(dp, 0, (size_t)2 * 128 * 1024 * 4, stream);

  for (int br = 0; br < 2; ++br) {
    const int F = br ? 128 : 256, logF = br ? 7 : 8, xstride = br ? 1024 : 2048;
    const float* x    = br ? target : drug;
    const float* W    = (const float*)d_in[br ? 10 : 2];
    const float* Wb   = (const float*)d_in[br ? 11 : 3];
    u16*         win  = br ? w_in_t : w_in_d;
    const float* inb  = (const float*)d_in[br ? 13 : 5];
    u16*         wout = br ? w_out_t : w_out_d;
    const float* outb = (const float*)d_in[br ? 15 : 7];
    const float* gg   = (const float*)d_in[br ? 16 : 8];
    const float* bb   = (const float*)d_in[br ? 17 : 9];
    float*       accp = br ? tp : dp;

    for (int b0 = 0; b0 < 128; b0 += Bc) {
      const int Mr = Bc * F;
      hgen<<<Mr * 128 / 256, 256, 0, stream>>>(x, W, Wb, hbuf, F, logF, b0, xstride, Mr * 128);
      gemm_ph<<<dim3(3072 / 128, Mr / 256), 512, 0, stream>>>(hbuf, win, inb, qkvbuf, Mr, 3072, 1024);
      attn<<<(F / 64) * 8 * Bc, 256, 0, stream>>>(qkvbuf, obuf, F);
      gemm_ph<<<dim3(1024 / 128, Mr / 256), 512, 0, stream>>>(obuf, wout, outb, projbuf, Mr, 1024, 1024);
      ln_fused<<<Mr / 64, 256, 0, stream>>>(projbuf, gg, bb, accp, F, b0);
    }
  }
  cosine_sig<<<128, 256, 0, stream>>>(dp, tp, (float*)d_out);
}

// Round 7
// 761.037 us; speedup vs baseline: 1.2303x; 1.2303x over previous
//
#include <hip/hip_runtime.h>

typedef unsigned short u16;
typedef unsigned int   u32;

using bf16x8 = __attribute__((ext_vector_type(8))) short;  // 8 bf16 in 4 VGPRs
using f32x4  = __attribute__((ext_vector_type(4))) float;

__device__ __forceinline__ float bf2f(u16 h) {
  u32 u = ((u32)h) << 16;
  return __builtin_bit_cast(float, u);
}
__device__ __forceinline__ u16 f2bf(float f) {   // round-to-nearest-even
  u32 u = __builtin_bit_cast(u32, f);
  u += 0x7fffu + ((u >> 16) & 1u);
  return (u16)(u >> 16);
}

__device__ __forceinline__ void gload16(const u16* src, u16* ldsdst) {
  __builtin_amdgcn_global_load_lds(
      (const __attribute__((address_space(1))) void*)src,
      (__attribute__((address_space(3))) void*)ldsdst, 16, 0, 0);
}

// m204 bijective XCD swizzle
__device__ __forceinline__ int xcd_swz(int wg, int nwg) {
  int q = nwg >> 3, r = nwg & 7, xcd = wg & 7, loc = wg >> 3;
  return (xcd < r ? xcd * (q + 1) : r * (q + 1) + (xcd - r) * q) + loc;
}

// ---------------------------------------------------------------------------
__global__ __launch_bounds__(256) void cvt_bf16(const float* __restrict__ in,
                                                u16* __restrict__ out, int n8) {
  int i = blockIdx.x * 256 + threadIdx.x;
  if (i >= n8) return;
  const float* p = in + (size_t)i * 8;
  bf16x8 o;
#pragma unroll
  for (int j = 0; j < 8; ++j) o[j] = (short)f2bf(p[j]);
  *(bf16x8*)(out + (size_t)i * 8) = o;
}

// ---------------------------------------------------------------------------
__global__ __launch_bounds__(256) void hgen(const float* __restrict__ x,
                                            const float* __restrict__ W,
                                            const float* __restrict__ bias,
                                            u16* __restrict__ h, int F, int logF,
                                            int b0, int xstride, int total8) {
  int idx = blockIdx.x * 256 + threadIdx.x;
  if (idx >= total8) return;
  int d0 = (idx & 127) << 3;
  int m  = idx >> 7;
  int f  = m & (F - 1);
  int b  = b0 + (m >> logF);
  float xv = x[(size_t)b * xstride + f];
  const float* wp = W + (size_t)f * 1024 + d0;
  const float* bp = bias + (size_t)f * 1024 + d0;
  bf16x8 o;
#pragma unroll
  for (int j = 0; j < 8; ++j) o[j] = (short)f2bf(fmaxf(xv * wp[j] + bp[j], 0.f));
  *(bf16x8*)(h + (size_t)m * 1024 + d0) = o;
}

// ---------------------------------------------------------------------------
// C(MxN, bf16) = A(MxK, bf16) * B^T (B stored NxK) + bias(N, f32)
// 256x128 tile, BK=32, 8 waves (4M x 2N), per-wave 64x64.
// TRIPLE-buffered (72 KB LDS -> 2 blocks/CU) with counted vmcnt.
__global__ __launch_bounds__(512, 4) void gemm_ph(const u16* __restrict__ A,
                                                  const u16* __restrict__ B,
                                                  const float* __restrict__ bias,
                                                  u16* __restrict__ C,
                                                  int M, int N, int K) {
  __shared__ u16 sA[3][256 * 32];   // 3 x 16 KB, chunk = 16 rows x 64 B
  __shared__ u16 sB[3][128 * 32];   // 3 x  8 KB
  const int tid  = threadIdx.x;
  const int lane = tid & 63;
  const int w    = tid >> 6;
  const int wm   = w >> 1;          // 0..3 : 64-row group
  const int wn   = w & 1;           // 0..1 : 64-col group

  const int nwg = gridDim.x * gridDim.y;
  const int wg  = blockIdx.y * gridDim.x + blockIdx.x;
  const int swz = xcd_swz(wg, nwg);
  const int n0 = (swz % gridDim.x) * 128;
  const int m0 = (swz / gridDim.x) * 256;

  f32x4 acc[4][4] = {};

  const int r_in  = lane >> 2;                       // 0..15 row within chunk
  const int s_src = (lane & 3) ^ ((lane >> 3) & 3);  // (l&3) ^ swz(r_in)

  auto stage = [&](int kt, int b) {
    const int k0 = kt << 5;
    gload16(A + (size_t)(m0 + w * 16 + r_in) * K + k0 + s_src * 8, &sA[b][w * 512]);
    gload16(A + (size_t)(m0 + (w + 8) * 16 + r_in) * K + k0 + s_src * 8, &sA[b][(w + 8) * 512]);
    gload16(B + (size_t)(n0 + w * 16 + r_in) * K + k0 + s_src * 8, &sB[b][w * 512]);
  };

  const int NT = K >> 5;
  stage(0, 0);
  stage(1, 1);
  asm volatile("s_waitcnt vmcnt(3)" ::: "memory");
  __builtin_amdgcn_s_barrier();

  int cur = 0, nx = 2;
  for (int t = 0; t < NT; ++t) {
    const bool more = (t + 2 < NT);
    if (more) stage(t + 2, nx);

    bf16x8 af[4], bg[4];
    const int g = lane >> 4;         // logical 16B k-slot
#pragma unroll
    for (int mf = 0; mf < 4; ++mf) {
      int ra = wm * 64 + mf * 16 + (lane & 15);
      af[mf] = *(const bf16x8*)(&sA[cur][ra * 32 + ((g ^ ((ra >> 1) & 3)) * 8)]);
    }
#pragma unroll
    for (int nf = 0; nf < 4; ++nf) {
      int rb = wn * 64 + nf * 16 + (lane & 15);
      bg[nf] = *(const bf16x8*)(&sB[cur][rb * 32 + ((g ^ ((rb >> 1) & 3)) * 8)]);
    }
    asm volatile("s_waitcnt lgkmcnt(0)" ::: "memory");
    __builtin_amdgcn_sched_barrier(0);
    __builtin_amdgcn_s_setprio(1);
#pragma unroll
    for (int mf = 0; mf < 4; ++mf)
#pragma unroll
      for (int nf = 0; nf < 4; ++nf)
        acc[mf][nf] = __builtin_amdgcn_mfma_f32_16x16x32_bf16(af[mf], bg[nf], acc[mf][nf], 0, 0, 0);
    __builtin_amdgcn_s_setprio(0);
    if (more) asm volatile("s_waitcnt vmcnt(3)" ::: "memory");
    else      asm volatile("s_waitcnt vmcnt(0)" ::: "memory");
    __builtin_amdgcn_s_barrier();
    cur = (cur == 2) ? 0 : cur + 1;
    nx  = (nx  == 2) ? 0 : nx  + 1;
  }

  // epilogue: D layout col = lane&15, row = (lane>>4)*4 + reg
#pragma unroll
  for (int nf = 0; nf < 4; ++nf) {
    int cl = n0 + wn * 64 + nf * 16 + (lane & 15);
    float bsv = bias[cl];
#pragma unroll
    for (int mf = 0; mf < 4; ++mf) {
      int r0 = m0 + wm * 64 + mf * 16 + (lane >> 4) * 4;
#pragma unroll
      for (int reg = 0; reg < 4; ++reg)
        C[(size_t)(r0 + reg) * N + cl] = f2bf(acc[mf][nf][reg] + bsv);
    }
  }
}

// ---------------------------------------------------------------------------
// Fused attention (r5 structure: coalesced staging, 1-D grid + XCD swizzle)
// + vT column XOR-swizzle: store col r ^ ((s&7)<<3) kills the ~32-way
// transpose-store bank conflict (now ~4-way); reads use the matching XOR
// (aligned: both terms are multiples of 8 u16 = 16 B).
__global__ __launch_bounds__(256) void attn(const u16* __restrict__ qkv,
                                            u16* __restrict__ o_out, int F) {
  __shared__ u16 q_lds[64 * 136];   // [64][128+8]
  __shared__ u16 k_lds[64 * 136];
  __shared__ u16 vT[128 * 72];      // [128 d][64+8 kpos], col-swizzled
  __shared__ u16 p_lds[4 * 16 * 72];// per-wave [16 qrow][64+8 kpos]

  const int tid  = threadIdx.x;
  const int lane = tid & 63;
  const int w    = tid >> 6;

  const int swzb = xcd_swz(blockIdx.x, gridDim.x);
  const int nqb = F >> 6;
  const int qb   = swzb % nqb;
  const int head = (swzb / nqb) & 7;
  const int bc   = swzb / (nqb * 8);

  const size_t rowbase = (size_t)bc * F * 3072;
  const float scale = 0.08838834764831845f;   // 1/sqrt(128)

  {
    const u16* qsrc = qkv + rowbase + (size_t)(qb * 64) * 3072 + head * 128;
    for (int it = tid; it < 1024; it += 256) {
      int r = it >> 4, s = it & 15;
      bf16x8 v = *(const bf16x8*)(qsrc + (size_t)r * 3072 + s * 8);
      bf16x8 o;
#pragma unroll
      for (int j = 0; j < 8; ++j) o[j] = (short)f2bf(bf2f((u16)v[j]) * scale);
      *(bf16x8*)(q_lds + r * 136 + s * 8) = o;
    }
  }

  f32x4 o_acc[8] = {};
  float m_run = -INFINITY, l_run = 0.f;
  const int qr = lane & 15;
  const int g4 = lane >> 4;

  const int nkb = F >> 6;
  for (int kb = 0; kb < nkb; ++kb) {
    __syncthreads();
    const u16* ksrc = qkv + rowbase + (size_t)(kb * 64) * 3072 + 1024 + head * 128;
    const u16* vsrc = qkv + rowbase + (size_t)(kb * 64) * 3072 + 2048 + head * 128;
    for (int it = tid; it < 1024; it += 256) {
      int r = it >> 4, s = it & 15;
      *(bf16x8*)(k_lds + r * 136 + s * 8) = *(const bf16x8*)(ksrc + (size_t)r * 3072 + s * 8);
      bf16x8 v = *(const bf16x8*)(vsrc + (size_t)r * 3072 + s * 8);
      int d0 = s * 8;
      int rs = r ^ ((s & 7) << 3);          // swizzled kpos column
#pragma unroll
      for (int j = 0; j < 8; ++j) vT[(d0 + j) * 72 + rs] = (u16)v[j];
    }
    __syncthreads();

    // S^T (64 kpos x 16 qrows): A = k rows, B = q^T
    f32x4 sa[4] = {};
#pragma unroll
    for (int kk = 0; kk < 4; ++kk) {
      bf16x8 bq = *(const bf16x8*)(q_lds + (w * 16 + qr) * 136 + kk * 32 + 8 * g4);
#pragma unroll
      for (int f = 0; f < 4; ++f) {
        bf16x8 ak = *(const bf16x8*)(k_lds + (f * 16 + qr) * 136 + kk * 32 + 8 * g4);
        sa[f] = __builtin_amdgcn_mfma_f32_16x16x32_bf16(ak, bq, sa[f], 0, 0, 0);
      }
    }

    float tmax = -INFINITY;
#pragma unroll
    for (int f = 0; f < 4; ++f)
#pragma unroll
      for (int rr = 0; rr < 4; ++rr) tmax = fmaxf(tmax, sa[f][rr]);
    tmax = fmaxf(tmax, __shfl_xor(tmax, 16));
    tmax = fmaxf(tmax, __shfl_xor(tmax, 32));
    float mnew  = fmaxf(m_run, tmax);
    float alpha = __expf(m_run - mnew);
    float psum  = 0.f;
#pragma unroll
    for (int f = 0; f < 4; ++f) {
      u16 pp[4];
#pragma unroll
      for (int rr = 0; rr < 4; ++rr) {
        float p = __expf(sa[f][rr] - mnew);
        psum += p;
        pp[rr] = f2bf(p);
      }
      uint2 u;
      u.x = (u32)pp[0] | ((u32)pp[1] << 16);
      u.y = (u32)pp[2] | ((u32)pp[3] << 16);
      *(uint2*)(p_lds + w * 1152 + qr * 72 + f * 16 + g4 * 4) = u;
    }
    psum += __shfl_xor(psum, 16);
    psum += __shfl_xor(psum, 32);
    l_run = l_run * alpha + psum;
    m_run = mnew;

#pragma unroll
    for (int rr = 0; rr < 4; ++rr) {
      float ar = __shfl(alpha, g4 * 4 + rr);
#pragma unroll
      for (int g = 0; g < 8; ++g) o_acc[g][rr] *= ar;
    }

    // PV: o[qrow, d] += P[qrow, kpos] * v[kpos, d]; vT read uses matching XOR
#pragma unroll
    for (int kk2 = 0; kk2 < 2; ++kk2) {
      bf16x8 pa = *(const bf16x8*)(p_lds + w * 1152 + qr * 72 + kk2 * 32 + 8 * g4);
#pragma unroll
      for (int g = 0; g < 8; ++g) {
        int swv = ((g * 2 + (qr >> 3)) & 7) << 3;   // ((d'>>3)&7)<<3, d' = g*16+qr
        bf16x8 vb = *(const bf16x8*)(vT + (g * 16 + qr) * 72 + ((kk2 * 32 + 8 * g4) ^ swv));
        o_acc[g] = __builtin_amdgcn_mfma_f32_16x16x32_bf16(pa, vb, o_acc[g], 0, 0, 0);
      }
    }
  }

  float linv = 1.f / l_run;
#pragma unroll
  for (int rr = 0; rr < 4; ++rr) {
    float lr = __shfl(linv, g4 * 4 + rr);
    size_t row = (size_t)bc * F + qb * 64 + w * 16 + g4 * 4 + rr;
#pragma unroll
    for (int g = 0; g < 8; ++g)
      o_out[row * 1024 + head * 128 + g * 16 + qr] = f2bf(o_acc[g][rr] * lr);
  }
}

// ---------------------------------------------------------------------------
__global__ __launch_bounds__(256) void ln_stats(const u16* __restrict__ proj,
                                                float2* __restrict__ stats) {
  int row  = blockIdx.x * 4 + (threadIdx.x >> 6);
  int lane = threadIdx.x & 63;
  const u16* p = proj + (size_t)row * 1024;
  float s = 0.f, s2 = 0.f;
#pragma unroll
  for (int i = 0; i < 2; ++i) {
    bf16x8 v = *(const bf16x8*)(p + (lane + i * 64) * 8);
#pragma unroll
    for (int j = 0; j < 8; ++j) { float f = bf2f((u16)v[j]); s += f; s2 += f * f; }
  }
#pragma unroll
  for (int m = 1; m < 64; m <<= 1) { s += __shfl_xor(s, m); s2 += __shfl_xor(s2, m); }
  if (lane == 0) {
    float mu  = s * (1.f / 1024.f);
    float var = s2 * (1.f / 1024.f) - mu * mu;
    stats[row] = make_float2(mu, rsqrtf(var + 1e-5f));
  }
}

__global__ __launch_bounds__(256) void ln_accum(const u16* __restrict__ proj,
                                                const float2* __restrict__ stats,
                                                const float* __restrict__ g,
                                                const float* __restrict__ beta,
                                                float* __restrict__ dp, int F, int b0) {
  int d  = blockIdx.x * 256 + threadIdx.x;
  int bc = blockIdx.z;
  int f0 = blockIdx.y * 64;
  const u16* base = proj + ((size_t)(bc * F + f0)) * 1024 + d;
  const float2* st = stats + bc * F + f0;
  float acc = 0.f;
  for (int f = 0; f < 64; ++f) {
    float2 s = st[f];
    acc += (bf2f(base[(size_t)f * 1024]) - s.x) * s.y;
  }
  acc = acc * g[d] + 64.f * beta[d];
  atomicAdd(&dp[(size_t)(b0 + bc) * 1024 + d], acc);
}

// ---------------------------------------------------------------------------
__global__ __launch_bounds__(256) void cosine_sig(const float* __restrict__ dp,
                                                  const float* __restrict__ tp,
                                                  float* __restrict__ out) {
  __shared__ float red[3][4];
  int b = blockIdx.x;
  int tid = threadIdx.x, lane = tid & 63, w = tid >> 6;
  float dot = 0.f, n1 = 0.f, n2 = 0.f;
  for (int i = tid; i < 1024; i += 256) {
    float a = dp[(size_t)b * 1024 + i], c = tp[(size_t)b * 1024 + i];
    dot += a * c; n1 += a * a; n2 += c * c;
  }
#pragma unroll
  for (int m = 1; m < 64; m <<= 1) {
    dot += __shfl_xor(dot, m); n1 += __shfl_xor(n1, m); n2 += __shfl_xor(n2, m);
  }
  if (lane == 0) { red[0][w] = dot; red[1][w] = n1; red[2][w] = n2; }
  __syncthreads();
  if (tid == 0) {
    dot = red[0][0] + red[0][1] + red[0][2] + red[0][3];
    n1  = red[1][0] + red[1][1] + red[1][2] + red[1][3];
    n2  = red[2][0] + red[2][1] + red[2][2] + red[2][3];
    float denom = fmaxf(sqrtf(n1) * sqrtf(n2), 1e-8f);
    out[b] = 1.f / (1.f + __expf(-dot / denom));
  }
}

// ---------------------------------------------------------------------------
extern "C" void kernel_launch(void* const* d_in, const int* in_sizes, int n_in,
                              void* d_out, int out_size, void* d_ws, size_t ws_size,
                              hipStream_t stream) {
  const float* drug   = (const float*)d_in[0];
  const float* target = (const float*)d_in[1];

  char* p = (char*)d_ws;
  auto alloc = [&](size_t bytes) -> char* {
    char* r = p; p += (bytes + 255) & ~(size_t)255; return r;
  };

  u16* w_in_d  = (u16*)alloc((size_t)3072 * 1024 * 2);
  u16* w_out_d = (u16*)alloc((size_t)1024 * 1024 * 2);
  u16* w_in_t  = (u16*)alloc((size_t)3072 * 1024 * 2);
  u16* w_out_t = (u16*)alloc((size_t)1024 * 1024 * 2);
  float* dp    = (float*)alloc((size_t)2 * 128 * 1024 * 4);
  float* tp    = dp + 128 * 1024;

  size_t fixed = (size_t)(p - (char*)d_ws);
  size_t per = (size_t)256 * 1024 * 2 * 3
             + (size_t)256 * 3072 * 2
             + (size_t)256 * 8 + 2048;
  int Bc = 8;
  if      (fixed + 128 * per <= ws_size) Bc = 128;
  else if (fixed +  64 * per <= ws_size) Bc = 64;
  else if (fixed +  32 * per <= ws_size) Bc = 32;
  else if (fixed +  16 * per <= ws_size) Bc = 16;

  u16* hbuf    = (u16*)alloc((size_t)Bc * 256 * 1024 * 2);
  u16* qkvbuf  = (u16*)alloc((size_t)Bc * 256 * 3072 * 2);
  u16* obuf    = (u16*)alloc((size_t)Bc * 256 * 1024 * 2);
  u16* projbuf = (u16*)alloc((size_t)Bc * 256 * 1024 * 2);
  float2* statsb = (float2*)alloc((size_t)Bc * 256 * 8);

  cvt_bf16<<<1536, 256, 0, stream>>>((const float*)d_in[4],  w_in_d,  3072 * 128);
  cvt_bf16<<<512,  256, 0, stream>>>((const float*)d_in[6],  w_out_d, 1024 * 128);
  cvt_bf16<<<1536, 256, 0, stream>>>((const float*)d_in[12], w_in_t,  3072 * 128);
  cvt_bf16<<<512,  256, 0, stream>>>((const float*)d_in[14], w_out_t, 1024 * 128);
  hipMemsetAsync(dp, 0, (size_t)2 * 128 * 1024 * 4, stream);

  for (int br = 0; br < 2; ++br) {
    const int F = br ? 128 : 256, logF = br ? 7 : 8, xstride = br ? 1024 : 2048;
    const float* x    = br ? target : drug;
    const float* W    = (const float*)d_in[br ? 10 : 2];
    const float* Wb   = (const float*)d_in[br ? 11 : 3];
    u16*         win  = br ? w_in_t : w_in_d;
    const float* inb  = (const float*)d_in[br ? 13 : 5];
    u16*         wout = br ? w_out_t : w_out_d;
    const float* outb = (const float*)d_in[br ? 15 : 7];
    const float* gg   = (const float*)d_in[br ? 16 : 8];
    const float* bb   = (const float*)d_in[br ? 17 : 9];
    float*       accp = br ? tp : dp;

    for (int b0 = 0; b0 < 128; b0 += Bc) {
      const int Mr = Bc * F;
      hgen<<<Mr * 128 / 256, 256, 0, stream>>>(x, W, Wb, hbuf, F, logF, b0, xstride, Mr * 128);
      gemm_ph<<<dim3(3072 / 128, Mr / 256), 512, 0, stream>>>(hbuf, win, inb, qkvbuf, Mr, 3072, 1024);
      attn<<<(F / 64) * 8 * Bc, 256, 0, stream>>>(qkvbuf, obuf, F);
      gemm_ph<<<dim3(1024 / 128, Mr / 256), 512, 0, stream>>>(obuf, wout, outb, projbuf, Mr, 1024, 1024);
      ln_stats<<<Mr / 4, 256, 0, stream>>>(projbuf, statsb);
      ln_accum<<<dim3(4, F / 64, Bc), 256, 0, stream>>>(projbuf, statsb, gg, bb, accp, F, b0);
    }
  }
  cosine_sig<<<128, 256, 0, stream>>>(dp, tp, (float*)d_out);
}

// Round 8
// 756.368 us; speedup vs baseline: 1.2379x; 1.0062x over previous
//
#include <hip/hip_runtime.h>

typedef unsigned short u16;
typedef unsigned int   u32;

using bf16x8 = __attribute__((ext_vector_type(8))) short;  // 8 bf16 in 4 VGPRs
using f32x4  = __attribute__((ext_vector_type(4))) float;

__device__ __forceinline__ float bf2f(u16 h) {
  u32 u = ((u32)h) << 16;
  return __builtin_bit_cast(float, u);
}
__device__ __forceinline__ u16 f2bf(float f) {   // round-to-nearest-even
  u32 u = __builtin_bit_cast(u32, f);
  u += 0x7fffu + ((u >> 16) & 1u);
  return (u16)(u >> 16);
}

__device__ __forceinline__ void gload16(const u16* src, u16* ldsdst) {
  __builtin_amdgcn_global_load_lds(
      (const __attribute__((address_space(1))) void*)src,
      (__attribute__((address_space(3))) void*)ldsdst, 16, 0, 0);
}

// m204 bijective XCD swizzle
__device__ __forceinline__ int xcd_swz(int wg, int nwg) {
  int q = nwg >> 3, r = nwg & 7, xcd = wg & 7, loc = wg >> 3;
  return (xcd < r ? xcd * (q + 1) : r * (q + 1) + (xcd - r) * q) + loc;
}

// ---------------------------------------------------------------------------
__global__ __launch_bounds__(256) void cvt_bf16(const float* __restrict__ in,
                                                u16* __restrict__ out, int n8) {
  int i = blockIdx.x * 256 + threadIdx.x;
  if (i >= n8) return;
  const float* p = in + (size_t)i * 8;
  bf16x8 o;
#pragma unroll
  for (int j = 0; j < 8; ++j) o[j] = (short)f2bf(p[j]);
  *(bf16x8*)(out + (size_t)i * 8) = o;
}

// ---------------------------------------------------------------------------
__global__ __launch_bounds__(256) void hgen(const float* __restrict__ x,
                                            const float* __restrict__ W,
                                            const float* __restrict__ bias,
                                            u16* __restrict__ h, int F, int logF,
                                            int b0, int xstride, int total8) {
  int idx = blockIdx.x * 256 + threadIdx.x;
  if (idx >= total8) return;
  int d0 = (idx & 127) << 3;
  int m  = idx >> 7;
  int f  = m & (F - 1);
  int b  = b0 + (m >> logF);
  float xv = x[(size_t)b * xstride + f];
  const float* wp = W + (size_t)f * 1024 + d0;
  const float* bp = bias + (size_t)f * 1024 + d0;
  bf16x8 o;
#pragma unroll
  for (int j = 0; j < 8; ++j) o[j] = (short)f2bf(fmaxf(xv * wp[j] + bp[j], 0.f));
  *(bf16x8*)(h + (size_t)m * 1024 + d0) = o;
}

// ---------------------------------------------------------------------------
// 8-phase 256x256 GEMM (m201 schedule), A/B test vs gemm_ph.
// Changes vs round-4 attempt: NO sched_barrier(0) in the phase prologue
// (m141: order-pinning regressed GEMM to 510 TF), launch_bounds (512,1).
// Requires M%256==0, N%256==0, K%128==0.
__global__ __launch_bounds__(512, 1) void gemm8p(const u16* __restrict__ A,
                                                 const u16* __restrict__ B,
                                                 const float* __restrict__ bias,
                                                 u16* __restrict__ C,
                                                 int M, int N, int K) {
  __shared__ u16 sA[2][16384];   // [buf][256 rows x 64 k]  (chunk = 8 rows = 1KB)
  __shared__ u16 sB[2][16384];
  const int tid  = threadIdx.x;
  const int lane = tid & 63;
  const int w    = tid >> 6;
  const int wm   = w >> 2;        // 0..1 : 128-row group
  const int wn   = w & 3;         // 0..3 : 64-col group

  const int nwg = gridDim.x * gridDim.y;
  const int wg  = blockIdx.y * gridDim.x + blockIdx.x;
  const int swz = xcd_swz(wg, nwg);
  const int n0 = (swz % gridDim.x) * 256;
  const int m0 = (swz / gridDim.x) * 256;

  f32x4 acc[8][4] = {};

  const int r_in  = lane >> 3;             // row within 8-row chunk
  const int s_log = (lane & 7) ^ r_in;     // pre-swizzled 16B slot to fetch

  auto stA = [&](int b, int half, int kt) {
    int c  = half * 8 + w;
    int k0 = kt << 6;
    gload16(A + (size_t)(m0 + c * 8 + r_in) * K + k0 + s_log * 8, &sA[b][c * 512]);
    gload16(A + (size_t)(m0 + (c + 16) * 8 + r_in) * K + k0 + s_log * 8, &sA[b][(c + 16) * 512]);
  };
  auto stB = [&](int b, int half, int kt) {
    int c  = half * 4 + (w & 3) + (w >> 2) * 8;
    int k0 = kt << 6;
    gload16(B + (size_t)(n0 + c * 8 + r_in) * K + k0 + s_log * 8, &sB[b][c * 512]);
    gload16(B + (size_t)(n0 + (c + 16) * 8 + r_in) * K + k0 + s_log * 8, &sB[b][(c + 16) * 512]);
  };

  bf16x8 af[4][2], bg0[2][2], bg1[2][2];

#define RD_A(b, rq)                                                              \
  _Pragma("unroll") for (int mf = 0; mf < 4; ++mf) {                             \
    int ra = wm * 128 + (rq) * 64 + mf * 16 + (lane & 15);                       \
    _Pragma("unroll") for (int kk = 0; kk < 2; ++kk) {                           \
      int sl = kk * 4 + (lane >> 4);                                             \
      af[mf][kk] = *(const bf16x8*)(&sA[b][ra * 64 + ((sl ^ (ra & 7)) * 8)]);    \
    }                                                                            \
  }
#define RD_B(b, cq, BG)                                                          \
  _Pragma("unroll") for (int nf = 0; nf < 2; ++nf) {                             \
    int rb = wn * 64 + (cq) * 32 + nf * 16 + (lane & 15);                        \
    _Pragma("unroll") for (int kk = 0; kk < 2; ++kk) {                           \
      int sl = kk * 4 + (lane >> 4);                                             \
      BG[nf][kk] = *(const bf16x8*)(&sB[b][rb * 64 + ((sl ^ (rb & 7)) * 8)]);    \
    }                                                                            \
  }
#define MMA_Q(rq, cq, BG)                                                        \
  _Pragma("unroll") for (int mf = 0; mf < 4; ++mf)                               \
  _Pragma("unroll") for (int nf = 0; nf < 2; ++nf)                               \
  _Pragma("unroll") for (int kk = 0; kk < 2; ++kk)                               \
    acc[(rq)*4+mf][(cq)*2+nf] = __builtin_amdgcn_mfma_f32_16x16x32_bf16(         \
        af[mf][kk], BG[nf][kk], acc[(rq)*4+mf][(cq)*2+nf], 0, 0, 0);
#define PH_SYNC()                                            \
  __builtin_amdgcn_s_barrier();                              \
  asm volatile("s_waitcnt lgkmcnt(0)" ::: "memory");         \
  __builtin_amdgcn_s_setprio(1)
#define PH_END()                                             \
  __builtin_amdgcn_s_setprio(0);                             \
  __builtin_amdgcn_s_barrier()
#define PH_END_VM6()                                         \
  __builtin_amdgcn_s_setprio(0);                             \
  asm volatile("s_waitcnt vmcnt(6)" ::: "memory");           \
  __builtin_amdgcn_s_barrier()
#define PH_END_VM0()                                         \
  __builtin_amdgcn_s_setprio(0);                             \
  asm volatile("s_waitcnt vmcnt(0)" ::: "memory");           \
  __builtin_amdgcn_s_barrier()

  const int NT = K >> 6;
  // prologue: tile0 -> buf0 (8 loads), tile1 Ar0/Bc0/Bc1 -> buf1 (6 loads)
  stA(0, 0, 0); stB(0, 0, 0); stB(0, 1, 0); stA(0, 1, 0);
  stA(1, 0, 1); stB(1, 0, 1); stB(1, 1, 1);
  asm volatile("s_waitcnt vmcnt(6)" ::: "memory");
  __builtin_amdgcn_s_barrier();

  const int niter = NT >> 1;
  for (int it = 0; it < niter; ++it) {
    const int t = it * 2;
    const bool nl = (it != niter - 1);   // not last

    // p1: Q00 of tile t (buf0)
    RD_A(0, 0); RD_B(0, 0, bg0);
    stA(1, 1, t + 1);
    PH_SYNC(); MMA_Q(0, 0, bg0); PH_END();
    // p2: Q01
    RD_B(0, 1, bg1);
    if (nl) stA(0, 0, t + 2);
    PH_SYNC(); MMA_Q(0, 1, bg1); PH_END();
    // p3: Q10
    RD_A(0, 1);
    if (nl) stB(0, 0, t + 2);
    PH_SYNC(); MMA_Q(1, 0, bg0); PH_END();
    // p4: Q11  (+vmcnt)
    if (nl) stB(0, 1, t + 2);
    PH_SYNC(); MMA_Q(1, 1, bg1);
    if (nl) { PH_END_VM6(); } else { PH_END_VM0(); }

    // p5: Q00 of tile t+1 (buf1)
    RD_A(1, 0); RD_B(1, 0, bg0);
    if (nl) stA(0, 1, t + 2);
    PH_SYNC(); MMA_Q(0, 0, bg0); PH_END();
    // p6: Q01
    RD_B(1, 1, bg1);
    if (nl) stA(1, 0, t + 3);
    PH_SYNC(); MMA_Q(0, 1, bg1); PH_END();
    // p7: Q10
    RD_A(1, 1);
    if (nl) stB(1, 0, t + 3);
    PH_SYNC(); MMA_Q(1, 0, bg0); PH_END();
    // p8: Q11  (+vmcnt)
    if (nl) stB(1, 1, t + 3);
    PH_SYNC(); MMA_Q(1, 1, bg1); PH_END_VM6();
  }

  // epilogue: D layout col = lane&15, row = (lane>>4)*4 + reg
#pragma unroll
  for (int i8 = 0; i8 < 8; ++i8) {
    int r0 = m0 + wm * 128 + i8 * 16 + (lane >> 4) * 4;
#pragma unroll
    for (int j4 = 0; j4 < 4; ++j4) {
      int cl = n0 + wn * 64 + j4 * 16 + (lane & 15);
      float bsv = bias[cl];
#pragma unroll
      for (int reg = 0; reg < 4; ++reg)
        C[(size_t)(r0 + reg) * N + cl] = f2bf(acc[i8][j4][reg] + bsv);
    }
  }
#undef RD_A
#undef RD_B
#undef MMA_Q
#undef PH_SYNC
#undef PH_END
#undef PH_END_VM6
#undef PH_END_VM0
}

// ---------------------------------------------------------------------------
// 2-phase control GEMM (866 TF): 256x128, BK=32, triple-buffer, counted vmcnt.
__global__ __launch_bounds__(512, 4) void gemm_ph(const u16* __restrict__ A,
                                                  const u16* __restrict__ B,
                                                  const float* __restrict__ bias,
                                                  u16* __restrict__ C,
                                                  int M, int N, int K) {
  __shared__ u16 sA[3][256 * 32];   // 3 x 16 KB, chunk = 16 rows x 64 B
  __shared__ u16 sB[3][128 * 32];   // 3 x  8 KB
  const int tid  = threadIdx.x;
  const int lane = tid & 63;
  const int w    = tid >> 6;
  const int wm   = w >> 1;          // 0..3 : 64-row group
  const int wn   = w & 1;           // 0..1 : 64-col group

  const int nwg = gridDim.x * gridDim.y;
  const int wg  = blockIdx.y * gridDim.x + blockIdx.x;
  const int swz = xcd_swz(wg, nwg);
  const int n0 = (swz % gridDim.x) * 128;
  const int m0 = (swz / gridDim.x) * 256;

  f32x4 acc[4][4] = {};

  const int r_in  = lane >> 2;                       // 0..15 row within chunk
  const int s_src = (lane & 3) ^ ((lane >> 3) & 3);  // (l&3) ^ swz(r_in)

  auto stage = [&](int kt, int b) {
    const int k0 = kt << 5;
    gload16(A + (size_t)(m0 + w * 16 + r_in) * K + k0 + s_src * 8, &sA[b][w * 512]);
    gload16(A + (size_t)(m0 + (w + 8) * 16 + r_in) * K + k0 + s_src * 8, &sA[b][(w + 8) * 512]);
    gload16(B + (size_t)(n0 + w * 16 + r_in) * K + k0 + s_src * 8, &sB[b][w * 512]);
  };

  const int NT = K >> 5;
  stage(0, 0);
  stage(1, 1);
  asm volatile("s_waitcnt vmcnt(3)" ::: "memory");
  __builtin_amdgcn_s_barrier();

  int cur = 0, nx = 2;
  for (int t = 0; t < NT; ++t) {
    const bool more = (t + 2 < NT);
    if (more) stage(t + 2, nx);

    bf16x8 af[4], bg[4];
    const int g = lane >> 4;         // logical 16B k-slot
#pragma unroll
    for (int mf = 0; mf < 4; ++mf) {
      int ra = wm * 64 + mf * 16 + (lane & 15);
      af[mf] = *(const bf16x8*)(&sA[cur][ra * 32 + ((g ^ ((ra >> 1) & 3)) * 8)]);
    }
#pragma unroll
    for (int nf = 0; nf < 4; ++nf) {
      int rb = wn * 64 + nf * 16 + (lane & 15);
      bg[nf] = *(const bf16x8*)(&sB[cur][rb * 32 + ((g ^ ((rb >> 1) & 3)) * 8)]);
    }
    asm volatile("s_waitcnt lgkmcnt(0)" ::: "memory");
    __builtin_amdgcn_sched_barrier(0);
    __builtin_amdgcn_s_setprio(1);
#pragma unroll
    for (int mf = 0; mf < 4; ++mf)
#pragma unroll
      for (int nf = 0; nf < 4; ++nf)
        acc[mf][nf] = __builtin_amdgcn_mfma_f32_16x16x32_bf16(af[mf], bg[nf], acc[mf][nf], 0, 0, 0);
    __builtin_amdgcn_s_setprio(0);
    if (more) asm volatile("s_waitcnt vmcnt(3)" ::: "memory");
    else      asm volatile("s_waitcnt vmcnt(0)" ::: "memory");
    __builtin_amdgcn_s_barrier();
    cur = (cur == 2) ? 0 : cur + 1;
    nx  = (nx  == 2) ? 0 : nx  + 1;
  }

  // epilogue: D layout col = lane&15, row = (lane>>4)*4 + reg
#pragma unroll
  for (int nf = 0; nf < 4; ++nf) {
    int cl = n0 + wn * 64 + nf * 16 + (lane & 15);
    float bsv = bias[cl];
#pragma unroll
    for (int mf = 0; mf < 4; ++mf) {
      int r0 = m0 + wm * 64 + mf * 16 + (lane >> 4) * 4;
#pragma unroll
      for (int reg = 0; reg < 4; ++reg)
        C[(size_t)(r0 + reg) * N + cl] = f2bf(acc[mf][nf][reg] + bsv);
    }
  }
}

// ---------------------------------------------------------------------------
// Fused attention (r7: coalesced staging, vT col XOR-swizzle, XCD swizzle).
__global__ __launch_bounds__(256) void attn(const u16* __restrict__ qkv,
                                            u16* __restrict__ o_out, int F) {
  __shared__ u16 q_lds[64 * 136];   // [64][128+8]
  __shared__ u16 k_lds[64 * 136];
  __shared__ u16 vT[128 * 72];      // [128 d][64+8 kpos], col-swizzled
  __shared__ u16 p_lds[4 * 16 * 72];// per-wave [16 qrow][64+8 kpos]

  const int tid  = threadIdx.x;
  const int lane = tid & 63;
  const int w    = tid >> 6;

  const int swzb = xcd_swz(blockIdx.x, gridDim.x);
  const int nqb = F >> 6;
  const int qb   = swzb % nqb;
  const int head = (swzb / nqb) & 7;
  const int bc   = swzb / (nqb * 8);

  const size_t rowbase = (size_t)bc * F * 3072;
  const float scale = 0.08838834764831845f;   // 1/sqrt(128)

  {
    const u16* qsrc = qkv + rowbase + (size_t)(qb * 64) * 3072 + head * 128;
    for (int it = tid; it < 1024; it += 256) {
      int r = it >> 4, s = it & 15;
      bf16x8 v = *(const bf16x8*)(qsrc + (size_t)r * 3072 + s * 8);
      bf16x8 o;
#pragma unroll
      for (int j = 0; j < 8; ++j) o[j] = (short)f2bf(bf2f((u16)v[j]) * scale);
      *(bf16x8*)(q_lds + r * 136 + s * 8) = o;
    }
  }

  f32x4 o_acc[8] = {};
  float m_run = -INFINITY, l_run = 0.f;
  const int qr = lane & 15;
  const int g4 = lane >> 4;

  const int nkb = F >> 6;
  for (int kb = 0; kb < nkb; ++kb) {
    __syncthreads();
    const u16* ksrc = qkv + rowbase + (size_t)(kb * 64) * 3072 + 1024 + head * 128;
    const u16* vsrc = qkv + rowbase + (size_t)(kb * 64) * 3072 + 2048 + head * 128;
    for (int it = tid; it < 1024; it += 256) {
      int r = it >> 4, s = it & 15;
      *(bf16x8*)(k_lds + r * 136 + s * 8) = *(const bf16x8*)(ksrc + (size_t)r * 3072 + s * 8);
      bf16x8 v = *(const bf16x8*)(vsrc + (size_t)r * 3072 + s * 8);
      int d0 = s * 8;
      int rs = r ^ ((s & 7) << 3);          // swizzled kpos column
#pragma unroll
      for (int j = 0; j < 8; ++j) vT[(d0 + j) * 72 + rs] = (u16)v[j];
    }
    __syncthreads();

    // S^T (64 kpos x 16 qrows): A = k rows, B = q^T
    f32x4 sa[4] = {};
#pragma unroll
    for (int kk = 0; kk < 4; ++kk) {
      bf16x8 bq = *(const bf16x8*)(q_lds + (w * 16 + qr) * 136 + kk * 32 + 8 * g4);
#pragma unroll
      for (int f = 0; f < 4; ++f) {
        bf16x8 ak = *(const bf16x8*)(k_lds + (f * 16 + qr) * 136 + kk * 32 + 8 * g4);
        sa[f] = __builtin_amdgcn_mfma_f32_16x16x32_bf16(ak, bq, sa[f], 0, 0, 0);
      }
    }

    float tmax = -INFINITY;
#pragma unroll
    for (int f = 0; f < 4; ++f)
#pragma unroll
      for (int rr = 0; rr < 4; ++rr) tmax = fmaxf(tmax, sa[f][rr]);
    tmax = fmaxf(tmax, __shfl_xor(tmax, 16));
    tmax = fmaxf(tmax, __shfl_xor(tmax, 32));
    float mnew  = fmaxf(m_run, tmax);
    float alpha = __expf(m_run - mnew);
    float psum  = 0.f;
#pragma unroll
    for (int f = 0; f < 4; ++f) {
      u16 pp[4];
#pragma unroll
      for (int rr = 0; rr < 4; ++rr) {
        float p = __expf(sa[f][rr] - mnew);
        psum += p;
        pp[rr] = f2bf(p);
      }
      uint2 u;
      u.x = (u32)pp[0] | ((u32)pp[1] << 16);
      u.y = (u32)pp[2] | ((u32)pp[3] << 16);
      *(uint2*)(p_lds + w * 1152 + qr * 72 + f * 16 + g4 * 4) = u;
    }
    psum += __shfl_xor(psum, 16);
    psum += __shfl_xor(psum, 32);
    l_run = l_run * alpha + psum;
    m_run = mnew;

#pragma unroll
    for (int rr = 0; rr < 4; ++rr) {
      float ar = __shfl(alpha, g4 * 4 + rr);
#pragma unroll
      for (int g = 0; g < 8; ++g) o_acc[g][rr] *= ar;
    }

    // PV: o[qrow, d] += P[qrow, kpos] * v[kpos, d]; vT read uses matching XOR
#pragma unroll
    for (int kk2 = 0; kk2 < 2; ++kk2) {
      bf16x8 pa = *(const bf16x8*)(p_lds + w * 1152 + qr * 72 + kk2 * 32 + 8 * g4);
#pragma unroll
      for (int g = 0; g < 8; ++g) {
        int swv = ((g * 2 + (qr >> 3)) & 7) << 3;   // ((d'>>3)&7)<<3, d' = g*16+qr
        bf16x8 vb = *(const bf16x8*)(vT + (g * 16 + qr) * 72 + ((kk2 * 32 + 8 * g4) ^ swv));
        o_acc[g] = __builtin_amdgcn_mfma_f32_16x16x32_bf16(pa, vb, o_acc[g], 0, 0, 0);
      }
    }
  }

  float linv = 1.f / l_run;
#pragma unroll
  for (int rr = 0; rr < 4; ++rr) {
    float lr = __shfl(linv, g4 * 4 + rr);
    size_t row = (size_t)bc * F + qb * 64 + w * 16 + g4 * 4 + rr;
#pragma unroll
    for (int g = 0; g < 8; ++g)
      o_out[row * 1024 + head * 128 + g * 16 + qr] = f2bf(o_acc[g][rr] * lr);
  }
}

// ---------------------------------------------------------------------------
__global__ __launch_bounds__(256) void ln_stats(const u16* __restrict__ proj,
                                                float2* __restrict__ stats) {
  int row  = blockIdx.x * 4 + (threadIdx.x >> 6);
  int lane = threadIdx.x & 63;
  const u16* p = proj + (size_t)row * 1024;
  float s = 0.f, s2 = 0.f;
#pragma unroll
  for (int i = 0; i < 2; ++i) {
    bf16x8 v = *(const bf16x8*)(p + (lane + i * 64) * 8);
#pragma unroll
    for (int j = 0; j < 8; ++j) { float f = bf2f((u16)v[j]); s += f; s2 += f * f; }
  }
#pragma unroll
  for (int m = 1; m < 64; m <<= 1) { s += __shfl_xor(s, m); s2 += __shfl_xor(s2, m); }
  if (lane == 0) {
    float mu  = s * (1.f / 1024.f);
    float var = s2 * (1.f / 1024.f) - mu * mu;
    stats[row] = make_float2(mu, rsqrtf(var + 1e-5f));
  }
}

__global__ __launch_bounds__(256) void ln_accum(const u16* __restrict__ proj,
                                                const float2* __restrict__ stats,
                                                const float* __restrict__ g,
                                                const float* __restrict__ beta,
                                                float* __restrict__ dp, int F, int b0) {
  int d  = blockIdx.x * 256 + threadIdx.x;
  int bc = blockIdx.z;
  int f0 = blockIdx.y * 64;
  const u16* base = proj + ((size_t)(bc * F + f0)) * 1024 + d;
  const float2* st = stats + bc * F + f0;
  float acc = 0.f;
  for (int f = 0; f < 64; ++f) {
    float2 s = st[f];
    acc += (bf2f(base[(size_t)f * 1024]) - s.x) * s.y;
  }
  acc = acc * g[d] + 64.f * beta[d];
  atomicAdd(&dp[(size_t)(b0 + bc) * 1024 + d], acc);
}

// ---------------------------------------------------------------------------
__global__ __launch_bounds__(256) void cosine_sig(const float* __restrict__ dp,
                                                  const float* __restrict__ tp,
                                                  float* __restrict__ out) {
  __shared__ float red[3][4];
  int b = blockIdx.x;
  int tid = threadIdx.x, lane = tid & 63, w = tid >> 6;
  float dot = 0.f, n1 = 0.f, n2 = 0.f;
  for (int i = tid; i < 1024; i += 256) {
    float a = dp[(size_t)b * 1024 + i], c = tp[(size_t)b * 1024 + i];
    dot += a * c; n1 += a * a; n2 += c * c;
  }
#pragma unroll
  for (int m = 1; m < 64; m <<= 1) {
    dot += __shfl_xor(dot, m); n1 += __shfl_xor(n1, m); n2 += __shfl_xor(n2, m);
  }
  if (lane == 0) { red[0][w] = dot; red[1][w] = n1; red[2][w] = n2; }
  __syncthreads();
  if (tid == 0) {
    dot = red[0][0] + red[0][1] + red[0][2] + red[0][3];
    n1  = red[1][0] + red[1][1] + red[1][2] + red[1][3];
    n2  = red[2][0] + red[2][1] + red[2][2] + red[2][3];
    float denom = fmaxf(sqrtf(n1) * sqrtf(n2), 1e-8f);
    out[b] = 1.f / (1.f + __expf(-dot / denom));
  }
}

// ---------------------------------------------------------------------------
extern "C" void kernel_launch(void* const* d_in, const int* in_sizes, int n_in,
                              void* d_out, int out_size, void* d_ws, size_t ws_size,
                              hipStream_t stream) {
  const float* drug   = (const float*)d_in[0];
  const float* target = (const float*)d_in[1];

  char* p = (char*)d_ws;
  auto alloc = [&](size_t bytes) -> char* {
    char* r = p; p += (bytes + 255) & ~(size_t)255; return r;
  };

  u16* w_in_d  = (u16*)alloc((size_t)3072 * 1024 * 2);
  u16* w_out_d = (u16*)alloc((size_t)1024 * 1024 * 2);
  u16* w_in_t  = (u16*)alloc((size_t)3072 * 1024 * 2);
  u16* w_out_t = (u16*)alloc((size_t)1024 * 1024 * 2);
  float* dp    = (float*)alloc((size_t)2 * 128 * 1024 * 4);
  float* tp    = dp + 128 * 1024;

  size_t fixed = (size_t)(p - (char*)d_ws);
  size_t per = (size_t)256 * 1024 * 2 * 3
             + (size_t)256 * 3072 * 2
             + (size_t)256 * 8 + 2048;
  int Bc = 8;
  if      (fixed + 128 * per <= ws_size) Bc = 128;
  else if (fixed +  64 * per <= ws_size) Bc = 64;
  else if (fixed +  32 * per <= ws_size) Bc = 32;
  else if (fixed +  16 * per <= ws_size) Bc = 16;

  u16* hbuf    = (u16*)alloc((size_t)Bc * 256 * 1024 * 2);
  u16* qkvbuf  = (u16*)alloc((size_t)Bc * 256 * 3072 * 2);
  u16* obuf    = (u16*)alloc((size_t)Bc * 256 * 1024 * 2);
  u16* projbuf = (u16*)alloc((size_t)Bc * 256 * 1024 * 2);
  float2* statsb = (float2*)alloc((size_t)Bc * 256 * 8);

  cvt_bf16<<<1536, 256, 0, stream>>>((const float*)d_in[4],  w_in_d,  3072 * 128);
  cvt_bf16<<<512,  256, 0, stream>>>((const float*)d_in[6],  w_out_d, 1024 * 128);
  cvt_bf16<<<1536, 256, 0, stream>>>((const float*)d_in[12], w_in_t,  3072 * 128);
  cvt_bf16<<<512,  256, 0, stream>>>((const float*)d_in[14], w_out_t, 1024 * 128);
  hipMemsetAsync(dp, 0, (size_t)2 * 128 * 1024 * 4, stream);

  for (int br = 0; br < 2; ++br) {
    const int F = br ? 128 : 256, logF = br ? 7 : 8, xstride = br ? 1024 : 2048;
    const float* x    = br ? target : drug;
    const float* W    = (const float*)d_in[br ? 10 : 2];
    const float* Wb   = (const float*)d_in[br ? 11 : 3];
    u16*         win  = br ? w_in_t : w_in_d;
    const float* inb  = (const float*)d_in[br ? 13 : 5];
    u16*         wout = br ? w_out_t : w_out_d;
    const float* outb = (const float*)d_in[br ? 15 : 7];
    const float* gg   = (const float*)d_in[br ? 16 : 8];
    const float* bb   = (const float*)d_in[br ? 17 : 9];
    float*       accp = br ? tp : dp;

    for (int b0 = 0; b0 < 128; b0 += Bc) {
      const int Mr = Bc * F;
      hgen<<<Mr * 128 / 256, 256, 0, stream>>>(x, W, Wb, hbuf, F, logF, b0, xstride, Mr * 128);
      gemm8p<<<dim3(3072 / 256, Mr / 256), 512, 0, stream>>>(hbuf, win, inb, qkvbuf, Mr, 3072, 1024);
      attn<<<(F / 64) * 8 * Bc, 256, 0, stream>>>(qkvbuf, obuf, F);
      gemm_ph<<<dim3(1024 / 128, Mr / 256), 512, 0, stream>>>(obuf, wout, outb, projbuf, Mr, 1024, 1024);
      ln_stats<<<Mr / 4, 256, 0, stream>>>(projbuf, statsb);
      ln_accum<<<dim3(4, F / 64, Bc), 256, 0, stream>>>(projbuf, statsb, gg, bb, accp, F, b0);
    }
  }
  cosine_sig<<<128, 256, 0, stream>>>(dp, tp, (float*)d_out);
}

// Round 9
// 674.730 us; speedup vs baseline: 1.3877x; 1.1210x over previous
//
#include <hip/hip_runtime.h>

typedef unsigned short u16;
typedef unsigned int   u32;

using bf16x8 = __attribute__((ext_vector_type(8))) short;  // 8 bf16 in 4 VGPRs
using f32x4  = __attribute__((ext_vector_type(4))) float;

__device__ __forceinline__ float bf2f(u16 h) {
  u32 u = ((u32)h) << 16;
  return __builtin_bit_cast(float, u);
}
__device__ __forceinline__ u16 f2bf(float f) {   // round-to-nearest-even
  u32 u = __builtin_bit_cast(u32, f);
  u += 0x7fffu + ((u >> 16) & 1u);
  return (u16)(u >> 16);
}

__device__ __forceinline__ void gload16(const u16* src, u16* ldsdst) {
  __builtin_amdgcn_global_load_lds(
      (const __attribute__((address_space(1))) void*)src,
      (__attribute__((address_space(3))) void*)ldsdst, 16, 0, 0);
}

// m204 bijective XCD swizzle
__device__ __forceinline__ int xcd_swz(int wg, int nwg) {
  int q = nwg >> 3, r = nwg & 7, xcd = wg & 7, loc = wg >> 3;
  return (xcd < r ? xcd * (q + 1) : r * (q + 1) + (xcd - r) * q) + loc;
}

// ---------------------------------------------------------------------------
__global__ __launch_bounds__(256) void cvt_bf16(const float* __restrict__ in,
                                                u16* __restrict__ out, int n8) {
  int i = blockIdx.x * 256 + threadIdx.x;
  if (i >= n8) return;
  const float* p = in + (size_t)i * 8;
  bf16x8 o;
#pragma unroll
  for (int j = 0; j < 8; ++j) o[j] = (short)f2bf(p[j]);
  *(bf16x8*)(out + (size_t)i * 8) = o;
}

// ---------------------------------------------------------------------------
__global__ __launch_bounds__(256) void hgen(const float* __restrict__ x,
                                            const float* __restrict__ W,
                                            const float* __restrict__ bias,
                                            u16* __restrict__ h, int F, int logF,
                                            int b0, int xstride, int total8) {
  int idx = blockIdx.x * 256 + threadIdx.x;
  if (idx >= total8) return;
  int d0 = (idx & 127) << 3;
  int m  = idx >> 7;
  int f  = m & (F - 1);
  int b  = b0 + (m >> logF);
  float xv = x[(size_t)b * xstride + f];
  const float* wp = W + (size_t)f * 1024 + d0;
  const float* bp = bias + (size_t)f * 1024 + d0;
  bf16x8 o;
#pragma unroll
  for (int j = 0; j < 8; ++j) o[j] = (short)f2bf(fmaxf(xv * wp[j] + bp[j], 0.f));
  *(bf16x8*)(h + (size_t)m * 1024 + d0) = o;
}

// ---------------------------------------------------------------------------
// 8-phase 256x256 GEMM (equal to 2-phase in time, better FETCH) — qkv GEMM.
// Requires M%256==0, N%256==0, K%128==0.
__global__ __launch_bounds__(512, 1) void gemm8p(const u16* __restrict__ A,
                                                 const u16* __restrict__ B,
                                                 const float* __restrict__ bias,
                                                 u16* __restrict__ C,
                                                 int M, int N, int K) {
  __shared__ u16 sA[2][16384];
  __shared__ u16 sB[2][16384];
  const int tid  = threadIdx.x;
  const int lane = tid & 63;
  const int w    = tid >> 6;
  const int wm   = w >> 2;
  const int wn   = w & 3;

  const int nwg = gridDim.x * gridDim.y;
  const int wg  = blockIdx.y * gridDim.x + blockIdx.x;
  const int swz = xcd_swz(wg, nwg);
  const int n0 = (swz % gridDim.x) * 256;
  const int m0 = (swz / gridDim.x) * 256;

  f32x4 acc[8][4] = {};

  const int r_in  = lane >> 3;
  const int s_log = (lane & 7) ^ r_in;

  auto stA = [&](int b, int half, int kt) {
    int c  = half * 8 + w;
    int k0 = kt << 6;
    gload16(A + (size_t)(m0 + c * 8 + r_in) * K + k0 + s_log * 8, &sA[b][c * 512]);
    gload16(A + (size_t)(m0 + (c + 16) * 8 + r_in) * K + k0 + s_log * 8, &sA[b][(c + 16) * 512]);
  };
  auto stB = [&](int b, int half, int kt) {
    int c  = half * 4 + (w & 3) + (w >> 2) * 8;
    int k0 = kt << 6;
    gload16(B + (size_t)(n0 + c * 8 + r_in) * K + k0 + s_log * 8, &sB[b][c * 512]);
    gload16(B + (size_t)(n0 + (c + 16) * 8 + r_in) * K + k0 + s_log * 8, &sB[b][(c + 16) * 512]);
  };

  bf16x8 af[4][2], bg0[2][2], bg1[2][2];

#define RD_A(b, rq)                                                              \
  _Pragma("unroll") for (int mf = 0; mf < 4; ++mf) {                             \
    int ra = wm * 128 + (rq) * 64 + mf * 16 + (lane & 15);                       \
    _Pragma("unroll") for (int kk = 0; kk < 2; ++kk) {                           \
      int sl = kk * 4 + (lane >> 4);                                             \
      af[mf][kk] = *(const bf16x8*)(&sA[b][ra * 64 + ((sl ^ (ra & 7)) * 8)]);    \
    }                                                                            \
  }
#define RD_B(b, cq, BG)                                                          \
  _Pragma("unroll") for (int nf = 0; nf < 2; ++nf) {                             \
    int rb = wn * 64 + (cq) * 32 + nf * 16 + (lane & 15);                        \
    _Pragma("unroll") for (int kk = 0; kk < 2; ++kk) {                           \
      int sl = kk * 4 + (lane >> 4);                                             \
      BG[nf][kk] = *(const bf16x8*)(&sB[b][rb * 64 + ((sl ^ (rb & 7)) * 8)]);    \
    }                                                                            \
  }
#define MMA_Q(rq, cq, BG)                                                        \
  _Pragma("unroll") for (int mf = 0; mf < 4; ++mf)                               \
  _Pragma("unroll") for (int nf = 0; nf < 2; ++nf)                               \
  _Pragma("unroll") for (int kk = 0; kk < 2; ++kk)                               \
    acc[(rq)*4+mf][(cq)*2+nf] = __builtin_amdgcn_mfma_f32_16x16x32_bf16(         \
        af[mf][kk], BG[nf][kk], acc[(rq)*4+mf][(cq)*2+nf], 0, 0, 0);
#define PH_SYNC()                                            \
  __builtin_amdgcn_s_barrier();                              \
  asm volatile("s_waitcnt lgkmcnt(0)" ::: "memory");         \
  __builtin_amdgcn_s_setprio(1)
#define PH_END()                                             \
  __builtin_amdgcn_s_setprio(0);                             \
  __builtin_amdgcn_s_barrier()
#define PH_END_VM6()                                         \
  __builtin_amdgcn_s_setprio(0);                             \
  asm volatile("s_waitcnt vmcnt(6)" ::: "memory");           \
  __builtin_amdgcn_s_barrier()
#define PH_END_VM0()                                         \
  __builtin_amdgcn_s_setprio(0);                             \
  asm volatile("s_waitcnt vmcnt(0)" ::: "memory");           \
  __builtin_amdgcn_s_barrier()

  const int NT = K >> 6;
  stA(0, 0, 0); stB(0, 0, 0); stB(0, 1, 0); stA(0, 1, 0);
  stA(1, 0, 1); stB(1, 0, 1); stB(1, 1, 1);
  asm volatile("s_waitcnt vmcnt(6)" ::: "memory");
  __builtin_amdgcn_s_barrier();

  const int niter = NT >> 1;
  for (int it = 0; it < niter; ++it) {
    const int t = it * 2;
    const bool nl = (it != niter - 1);

    RD_A(0, 0); RD_B(0, 0, bg0);
    stA(1, 1, t + 1);
    PH_SYNC(); MMA_Q(0, 0, bg0); PH_END();
    RD_B(0, 1, bg1);
    if (nl) stA(0, 0, t + 2);
    PH_SYNC(); MMA_Q(0, 1, bg1); PH_END();
    RD_A(0, 1);
    if (nl) stB(0, 0, t + 2);
    PH_SYNC(); MMA_Q(1, 0, bg0); PH_END();
    if (nl) stB(0, 1, t + 2);
    PH_SYNC(); MMA_Q(1, 1, bg1);
    if (nl) { PH_END_VM6(); } else { PH_END_VM0(); }

    RD_A(1, 0); RD_B(1, 0, bg0);
    if (nl) stA(0, 1, t + 2);
    PH_SYNC(); MMA_Q(0, 0, bg0); PH_END();
    RD_B(1, 1, bg1);
    if (nl) stA(1, 0, t + 3);
    PH_SYNC(); MMA_Q(0, 1, bg1); PH_END();
    RD_A(1, 1);
    if (nl) stB(1, 0, t + 3);
    PH_SYNC(); MMA_Q(1, 0, bg0); PH_END();
    if (nl) stB(1, 1, t + 3);
    PH_SYNC(); MMA_Q(1, 1, bg1); PH_END_VM6();
  }

#pragma unroll
  for (int i8 = 0; i8 < 8; ++i8) {
    int r0 = m0 + wm * 128 + i8 * 16 + (lane >> 4) * 4;
#pragma unroll
    for (int j4 = 0; j4 < 4; ++j4) {
      int cl = n0 + wn * 64 + j4 * 16 + (lane & 15);
      float bsv = bias[cl];
#pragma unroll
      for (int reg = 0; reg < 4; ++reg)
        C[(size_t)(r0 + reg) * N + cl] = f2bf(acc[i8][j4][reg] + bsv);
    }
  }
#undef RD_A
#undef RD_B
#undef MMA_Q
#undef PH_SYNC
#undef PH_END
#undef PH_END_VM6
#undef PH_END_VM0
}

// ---------------------------------------------------------------------------
// 2-phase GEMM (866 TF): 256x128, BK=32, triple-buffer, counted vmcnt — out-proj.
__global__ __launch_bounds__(512, 4) void gemm_ph(const u16* __restrict__ A,
                                                  const u16* __restrict__ B,
                                                  const float* __restrict__ bias,
                                                  u16* __restrict__ C,
                                                  int M, int N, int K) {
  __shared__ u16 sA[3][256 * 32];
  __shared__ u16 sB[3][128 * 32];
  const int tid  = threadIdx.x;
  const int lane = tid & 63;
  const int w    = tid >> 6;
  const int wm   = w >> 1;
  const int wn   = w & 1;

  const int nwg = gridDim.x * gridDim.y;
  const int wg  = blockIdx.y * gridDim.x + blockIdx.x;
  const int swz = xcd_swz(wg, nwg);
  const int n0 = (swz % gridDim.x) * 128;
  const int m0 = (swz / gridDim.x) * 256;

  f32x4 acc[4][4] = {};

  const int r_in  = lane >> 2;
  const int s_src = (lane & 3) ^ ((lane >> 3) & 3);

  auto stage = [&](int kt, int b) {
    const int k0 = kt << 5;
    gload16(A + (size_t)(m0 + w * 16 + r_in) * K + k0 + s_src * 8, &sA[b][w * 512]);
    gload16(A + (size_t)(m0 + (w + 8) * 16 + r_in) * K + k0 + s_src * 8, &sA[b][(w + 8) * 512]);
    gload16(B + (size_t)(n0 + w * 16 + r_in) * K + k0 + s_src * 8, &sB[b][w * 512]);
  };

  const int NT = K >> 5;
  stage(0, 0);
  stage(1, 1);
  asm volatile("s_waitcnt vmcnt(3)" ::: "memory");
  __builtin_amdgcn_s_barrier();

  int cur = 0, nx = 2;
  for (int t = 0; t < NT; ++t) {
    const bool more = (t + 2 < NT);
    if (more) stage(t + 2, nx);

    bf16x8 af[4], bg[4];
    const int g = lane >> 4;
#pragma unroll
    for (int mf = 0; mf < 4; ++mf) {
      int ra = wm * 64 + mf * 16 + (lane & 15);
      af[mf] = *(const bf16x8*)(&sA[cur][ra * 32 + ((g ^ ((ra >> 1) & 3)) * 8)]);
    }
#pragma unroll
    for (int nf = 0; nf < 4; ++nf) {
      int rb = wn * 64 + nf * 16 + (lane & 15);
      bg[nf] = *(const bf16x8*)(&sB[cur][rb * 32 + ((g ^ ((rb >> 1) & 3)) * 8)]);
    }
    asm volatile("s_waitcnt lgkmcnt(0)" ::: "memory");
    __builtin_amdgcn_sched_barrier(0);
    __builtin_amdgcn_s_setprio(1);
#pragma unroll
    for (int mf = 0; mf < 4; ++mf)
#pragma unroll
      for (int nf = 0; nf < 4; ++nf)
        acc[mf][nf] = __builtin_amdgcn_mfma_f32_16x16x32_bf16(af[mf], bg[nf], acc[mf][nf], 0, 0, 0);
    __builtin_amdgcn_s_setprio(0);
    if (more) asm volatile("s_waitcnt vmcnt(3)" ::: "memory");
    else      asm volatile("s_waitcnt vmcnt(0)" ::: "memory");
    __builtin_amdgcn_s_barrier();
    cur = (cur == 2) ? 0 : cur + 1;
    nx  = (nx  == 2) ? 0 : nx  + 1;
  }

#pragma unroll
  for (int nf = 0; nf < 4; ++nf) {
    int cl = n0 + wn * 64 + nf * 16 + (lane & 15);
    float bsv = bias[cl];
#pragma unroll
    for (int mf = 0; mf < 4; ++mf) {
      int r0 = m0 + wm * 64 + mf * 16 + (lane >> 4) * 4;
#pragma unroll
      for (int reg = 0; reg < 4; ++reg)
        C[(size_t)(r0 + reg) * N + cl] = f2bf(acc[mf][nf][reg] + bsv);
    }
  }
}

// ---------------------------------------------------------------------------
// Fused attention, QBLK=128: 8 waves (512 thr), each wave owns 16 q-rows.
// K/V staging (32 KB per 64-kpos tile) amortized over 128 q-rows (2x r8).
// vT transpose writes as ds_write_b32 pairs (4x fewer LDS write instrs).
// Grid: nqb(F/128) x 8 heads x nb batches, 1-D + XCD swizzle.
__global__ __launch_bounds__(512) void attn(const u16* __restrict__ qkv,
                                            u16* __restrict__ o_out, int F) {
  __shared__ u16 q_lds[128 * 136];   // [128][128+8]
  __shared__ u16 k_lds[64 * 136];
  __shared__ u16 vT[128 * 72];       // [128 d][64+8 kpos], col-swizzled
  __shared__ u16 p_lds[8 * 16 * 72]; // per-wave [16 qrow][64+8 kpos]

  const int tid  = threadIdx.x;
  const int lane = tid & 63;
  const int w    = tid >> 6;          // 0..7

  const int swzb = xcd_swz(blockIdx.x, gridDim.x);
  const int nqb  = F >> 7;            // 256->2, 128->1
  const int qb   = swzb % nqb;
  const int head = (swzb / nqb) & 7;
  const int bc   = swzb / (nqb * 8);

  const size_t rowbase = (size_t)bc * F * 3072;
  const float scale = 0.08838834764831845f;   // 1/sqrt(128)

  {
    const u16* qsrc = qkv + rowbase + (size_t)(qb * 128) * 3072 + head * 128;
    for (int it = tid; it < 2048; it += 512) {
      int r = it >> 4, s = it & 15;
      bf16x8 v = *(const bf16x8*)(qsrc + (size_t)r * 3072 + s * 8);
      bf16x8 o;
#pragma unroll
      for (int j = 0; j < 8; ++j) o[j] = (short)f2bf(bf2f((u16)v[j]) * scale);
      *(bf16x8*)(q_lds + r * 136 + s * 8) = o;
    }
  }

  f32x4 o_acc[8] = {};
  float m_run = -INFINITY, l_run = 0.f;
  const int qr = lane & 15;
  const int g4 = lane >> 4;

  const int nkb = F >> 6;
  for (int kb = 0; kb < nkb; ++kb) {
    __syncthreads();
    const u16* ksrc = qkv + rowbase + (size_t)(kb * 64) * 3072 + 1024 + head * 128;
    const u16* vsrc = ksrc + 1024;
    // K: 64 rows x 16 slots over 512 threads = 2 iters
    for (int it = tid; it < 1024; it += 512) {
      int r = it >> 4, s = it & 15;
      *(bf16x8*)(k_lds + r * 136 + s * 8) = *(const bf16x8*)(ksrc + (size_t)r * 3072 + s * 8);
    }
    // V: 32 row-pairs x 16 slots = exactly 512 items
    {
      int g2 = tid >> 4, s = tid & 15;
      const u16* v0 = vsrc + (size_t)(2 * g2) * 3072 + s * 8;
      bf16x8 a = *(const bf16x8*)(v0);
      bf16x8 b = *(const bf16x8*)(v0 + 3072);
      int rs0 = (2 * g2) ^ ((s & 7) << 3);          // swizzled kpos (even)
      int d0  = s * 8;
#pragma unroll
      for (int j = 0; j < 8; ++j) {
        u32 pk = (u32)(u16)a[j] | ((u32)(u16)b[j] << 16);
        *(u32*)(vT + (d0 + j) * 72 + rs0) = pk;
      }
    }
    __syncthreads();

    // S^T (64 kpos x 16 qrows): A = k rows, B = q^T
    f32x4 sa[4] = {};
#pragma unroll
    for (int kk = 0; kk < 4; ++kk) {
      bf16x8 bq = *(const bf16x8*)(q_lds + (w * 16 + qr) * 136 + kk * 32 + 8 * g4);
#pragma unroll
      for (int f = 0; f < 4; ++f) {
        bf16x8 ak = *(const bf16x8*)(k_lds + (f * 16 + qr) * 136 + kk * 32 + 8 * g4);
        sa[f] = __builtin_amdgcn_mfma_f32_16x16x32_bf16(ak, bq, sa[f], 0, 0, 0);
      }
    }

    float tmax = -INFINITY;
#pragma unroll
    for (int f = 0; f < 4; ++f)
#pragma unroll
      for (int rr = 0; rr < 4; ++rr) tmax = fmaxf(tmax, sa[f][rr]);
    tmax = fmaxf(tmax, __shfl_xor(tmax, 16));
    tmax = fmaxf(tmax, __shfl_xor(tmax, 32));
    float mnew  = fmaxf(m_run, tmax);
    float alpha = __expf(m_run - mnew);
    float psum  = 0.f;
#pragma unroll
    for (int f = 0; f < 4; ++f) {
      u16 pp[4];
#pragma unroll
      for (int rr = 0; rr < 4; ++rr) {
        float p = __expf(sa[f][rr] - mnew);
        psum += p;
        pp[rr] = f2bf(p);
      }
      uint2 u;
      u.x = (u32)pp[0] | ((u32)pp[1] << 16);
      u.y = (u32)pp[2] | ((u32)pp[3] << 16);
      *(uint2*)(p_lds + w * 1152 + qr * 72 + f * 16 + g4 * 4) = u;
    }
    psum += __shfl_xor(psum, 16);
    psum += __shfl_xor(psum, 32);
    l_run = l_run * alpha + psum;
    m_run = mnew;

#pragma unroll
    for (int rr = 0; rr < 4; ++rr) {
      float ar = __shfl(alpha, g4 * 4 + rr);
#pragma unroll
      for (int g = 0; g < 8; ++g) o_acc[g][rr] *= ar;
    }

    // PV: o[qrow, d] += P[qrow, kpos] * v[kpos, d]; vT read uses matching XOR
#pragma unroll
    for (int kk2 = 0; kk2 < 2; ++kk2) {
      bf16x8 pa = *(const bf16x8*)(p_lds + w * 1152 + qr * 72 + kk2 * 32 + 8 * g4);
#pragma unroll
      for (int g = 0; g < 8; ++g) {
        int swv = ((g * 2 + (qr >> 3)) & 7) << 3;   // ((d'>>3)&7)<<3, d' = g*16+qr
        bf16x8 vb = *(const bf16x8*)(vT + (g * 16 + qr) * 72 + ((kk2 * 32 + 8 * g4) ^ swv));
        o_acc[g] = __builtin_amdgcn_mfma_f32_16x16x32_bf16(pa, vb, o_acc[g], 0, 0, 0);
      }
    }
  }

  float linv = 1.f / l_run;
#pragma unroll
  for (int rr = 0; rr < 4; ++rr) {
    float lr = __shfl(linv, g4 * 4 + rr);
    size_t row = (size_t)bc * F + qb * 128 + w * 16 + g4 * 4 + rr;
#pragma unroll
    for (int g = 0; g < 8; ++g)
      o_out[row * 1024 + head * 128 + g * 16 + qr] = f2bf(o_acc[g][rr] * lr);
  }
}

// ---------------------------------------------------------------------------
__global__ __launch_bounds__(256) void ln_stats(const u16* __restrict__ proj,
                                                float2* __restrict__ stats) {
  int row  = blockIdx.x * 4 + (threadIdx.x >> 6);
  int lane = threadIdx.x & 63;
  const u16* p = proj + (size_t)row * 1024;
  float s = 0.f, s2 = 0.f;
#pragma unroll
  for (int i = 0; i < 2; ++i) {
    bf16x8 v = *(const bf16x8*)(p + (lane + i * 64) * 8);
#pragma unroll
    for (int j = 0; j < 8; ++j) { float f = bf2f((u16)v[j]); s += f; s2 += f * f; }
  }
#pragma unroll
  for (int m = 1; m < 64; m <<= 1) { s += __shfl_xor(s, m); s2 += __shfl_xor(s2, m); }
  if (lane == 0) {
    float mu  = s * (1.f / 1024.f);
    float var = s2 * (1.f / 1024.f) - mu * mu;
    stats[row] = make_float2(mu, rsqrtf(var + 1e-5f));
  }
}

__global__ __launch_bounds__(256) void ln_accum(const u16* __restrict__ proj,
                                                const float2* __restrict__ stats,
                                                const float* __restrict__ g,
                                                const float* __restrict__ beta,
                                                float* __restrict__ dp, int F, int b0) {
  int d  = blockIdx.x * 256 + threadIdx.x;
  int bc = blockIdx.z;
  int f0 = blockIdx.y * 64;
  const u16* base = proj + ((size_t)(bc * F + f0)) * 1024 + d;
  const float2* st = stats + bc * F + f0;
  float acc = 0.f;
  for (int f = 0; f < 64; ++f) {
    float2 s = st[f];
    acc += (bf2f(base[(size_t)f * 1024]) - s.x) * s.y;
  }
  acc = acc * g[d] + 64.f * beta[d];
  atomicAdd(&dp[(size_t)(b0 + bc) * 1024 + d], acc);
}

// ---------------------------------------------------------------------------
__global__ __launch_bounds__(256) void cosine_sig(const float* __restrict__ dp,
                                                  const float* __restrict__ tp,
                                                  float* __restrict__ out) {
  __shared__ float red[3][4];
  int b = blockIdx.x;
  int tid = threadIdx.x, lane = tid & 63, w = tid >> 6;
  float dot = 0.f, n1 = 0.f, n2 = 0.f;
  for (int i = tid; i < 1024; i += 256) {
    float a = dp[(size_t)b * 1024 + i], c = tp[(size_t)b * 1024 + i];
    dot += a * c; n1 += a * a; n2 += c * c;
  }
#pragma unroll
  for (int m = 1; m < 64; m <<= 1) {
    dot += __shfl_xor(dot, m); n1 += __shfl_xor(n1, m); n2 += __shfl_xor(n2, m);
  }
  if (lane == 0) { red[0][w] = dot; red[1][w] = n1; red[2][w] = n2; }
  __syncthreads();
  if (tid == 0) {
    dot = red[0][0] + red[0][1] + red[0][2] + red[0][3];
    n1  = red[1][0] + red[1][1] + red[1][2] + red[1][3];
    n2  = red[2][0] + red[2][1] + red[2][2] + red[2][3];
    float denom = fmaxf(sqrtf(n1) * sqrtf(n2), 1e-8f);
    out[b] = 1.f / (1.f + __expf(-dot / denom));
  }
}

// ---------------------------------------------------------------------------
extern "C" void kernel_launch(void* const* d_in, const int* in_sizes, int n_in,
                              void* d_out, int out_size, void* d_ws, size_t ws_size,
                              hipStream_t stream) {
  const float* drug   = (const float*)d_in[0];
  const float* target = (const float*)d_in[1];

  char* p = (char*)d_ws;
  auto alloc = [&](size_t bytes) -> char* {
    char* r = p; p += (bytes + 255) & ~(size_t)255; return r;
  };

  u16* w_in_d  = (u16*)alloc((size_t)3072 * 1024 * 2);
  u16* w_out_d = (u16*)alloc((size_t)1024 * 1024 * 2);
  u16* w_in_t  = (u16*)alloc((size_t)3072 * 1024 * 2);
  u16* w_out_t = (u16*)alloc((size_t)1024 * 1024 * 2);
  float* dp    = (float*)alloc((size_t)2 * 128 * 1024 * 4);
  float* tp    = dp + 128 * 1024;

  size_t fixed = (size_t)(p - (char*)d_ws);
  size_t per = (size_t)256 * 1024 * 2 * 3
             + (size_t)256 * 3072 * 2
             + (size_t)256 * 8 + 2048;
  int Bc = 8;
  if      (fixed + 128 * per <= ws_size) Bc = 128;
  else if (fixed +  64 * per <= ws_size) Bc = 64;
  else if (fixed +  32 * per <= ws_size) Bc = 32;
  else if (fixed +  16 * per <= ws_size) Bc = 16;

  u16* hbuf    = (u16*)alloc((size_t)Bc * 256 * 1024 * 2);
  u16* qkvbuf  = (u16*)alloc((size_t)Bc * 256 * 3072 * 2);
  u16* obuf    = (u16*)alloc((size_t)Bc * 256 * 1024 * 2);
  u16* projbuf = (u16*)alloc((size_t)Bc * 256 * 1024 * 2);
  float2* statsb = (float2*)alloc((size_t)Bc * 256 * 8);

  cvt_bf16<<<1536, 256, 0, stream>>>((const float*)d_in[4],  w_in_d,  3072 * 128);
  cvt_bf16<<<512,  256, 0, stream>>>((const float*)d_in[6],  w_out_d, 1024 * 128);
  cvt_bf16<<<1536, 256, 0, stream>>>((const float*)d_in[12], w_in_t,  3072 * 128);
  cvt_bf16<<<512,  256, 0, stream>>>((const float*)d_in[14], w_out_t, 1024 * 128);
  hipMemsetAsync(dp, 0, (size_t)2 * 128 * 1024 * 4, stream);

  for (int br = 0; br < 2; ++br) {
    const int F = br ? 128 : 256, logF = br ? 7 : 8, xstride = br ? 1024 : 2048;
    const float* x    = br ? target : drug;
    const float* W    = (const float*)d_in[br ? 10 : 2];
    const float* Wb   = (const float*)d_in[br ? 11 : 3];
    u16*         win  = br ? w_in_t : w_in_d;
    const float* inb  = (const float*)d_in[br ? 13 : 5];
    u16*         wout = br ? w_out_t : w_out_d;
    const float* outb = (const float*)d_in[br ? 15 : 7];
    const float* gg   = (const float*)d_in[br ? 16 : 8];
    const float* bb   = (const float*)d_in[br ? 17 : 9];
    float*       accp = br ? tp : dp;

    // batches per chunk: buffers hold Bc*256 rows; target rows/batch = 128
    const int nb = (br ? (2 * Bc > 128 ? 128 : 2 * Bc) : (Bc > 128 ? 128 : Bc));

    for (int b0 = 0; b0 < 128; b0 += nb) {
      const int Mr = nb * F;
      hgen<<<Mr * 128 / 256, 256, 0, stream>>>(x, W, Wb, hbuf, F, logF, b0, xstride, Mr * 128);
      gemm8p<<<dim3(3072 / 256, Mr / 256), 512, 0, stream>>>(hbuf, win, inb, qkvbuf, Mr, 3072, 1024);
      attn<<<(F / 128) * 8 * nb, 512, 0, stream>>>(qkvbuf, obuf, F);
      gemm_ph<<<dim3(1024 / 128, Mr / 256), 512, 0, stream>>>(obuf, wout, outb, projbuf, Mr, 1024, 1024);
      ln_stats<<<Mr / 4, 256, 0, stream>>>(projbuf, statsb);
      ln_accum<<<dim3(4, F / 64, nb), 256, 0, stream>>>(projbuf, statsb, gg, bb, accp, F, b0);
    }
  }
  cosine_sig<<<128, 256, 0, stream>>>(dp, tp, (float*)d_out);
}

// Round 10
// 618.902 us; speedup vs baseline: 1.5128x; 1.0902x over previous
//
#include <hip/hip_runtime.h>

typedef unsigned short u16;
typedef unsigned int   u32;
typedef unsigned char  u8;

using bf16x8 = __attribute__((ext_vector_type(8))) short;  // 8 bf16 in 4 VGPRs
using f32x4  = __attribute__((ext_vector_type(4))) float;
using i32x4  = __attribute__((ext_vector_type(4))) int;    // 16 i8 operand / i32 acc

__device__ __forceinline__ float bf2f(u16 h) {
  u32 u = ((u32)h) << 16;
  return __builtin_bit_cast(float, u);
}
__device__ __forceinline__ u16 f2bf(float f) {   // round-to-nearest-even
  u32 u = __builtin_bit_cast(u32, f);
  u += 0x7fffu + ((u >> 16) & 1u);
  return (u16)(u >> 16);
}

__device__ __forceinline__ void gload16(const void* src, void* ldsdst) {
  __builtin_amdgcn_global_load_lds(
      (const __attribute__((address_space(1))) void*)src,
      (__attribute__((address_space(3))) void*)ldsdst, 16, 0, 0);
}

// i8 MFMA via inline asm (ISA 10: v_mfma_i32_16x16x64_i8 a[0:3], v[0:3], v[4:7], a[0:3])
__device__ __forceinline__ void mfma_i8(i32x4& c, i32x4 a, i32x4 b) {
  asm volatile("v_mfma_i32_16x16x64_i8 %0, %1, %2, %0" : "+a"(c) : "v"(a), "v"(b));
}

// m204 bijective XCD swizzle
__device__ __forceinline__ int xcd_swz(int wg, int nwg) {
  int q = nwg >> 3, r = nwg & 7, xcd = wg & 7, loc = wg >> 3;
  return (xcd < r ? xcd * (q + 1) : r * (q + 1) + (xcd - r) * q) + loc;
}

// ---------------------------------------------------------------------------
__global__ __launch_bounds__(256) void cvt_bf16(const float* __restrict__ in,
                                                u16* __restrict__ out, int n8) {
  int i = blockIdx.x * 256 + threadIdx.x;
  if (i >= n8) return;
  const float* p = in + (size_t)i * 8;
  bf16x8 o;
#pragma unroll
  for (int j = 0; j < 8; ++j) o[j] = (short)f2bf(p[j]);
  *(bf16x8*)(out + (size_t)i * 8) = o;
}

// ---------------------------------------------------------------------------
// per-row (n over K=1024) signed-i8 quantization of a weight matrix
__global__ __launch_bounds__(256) void cvt_w_i8(const float* __restrict__ in,
                                                u8* __restrict__ out,
                                                float* __restrict__ sc) {
  const int row  = blockIdx.x * 4 + (threadIdx.x >> 6);
  const int lane = threadIdx.x & 63;
  const float4* p = (const float4*)(in + (size_t)row * 1024 + lane * 16);
  float v[16];
  float mx = 0.f;
#pragma unroll
  for (int i = 0; i < 4; ++i) {
    float4 t = p[i];
    v[i * 4 + 0] = t.x; v[i * 4 + 1] = t.y; v[i * 4 + 2] = t.z; v[i * 4 + 3] = t.w;
#pragma unroll
    for (int j = 0; j < 4; ++j) mx = fmaxf(mx, fabsf(v[i * 4 + j]));
  }
#pragma unroll
  for (int m = 1; m < 64; m <<= 1) mx = fmaxf(mx, __shfl_xor(mx, m));
  const float scale = mx > 0.f ? 127.f / mx : 0.f;
  u32 pk[4];
#pragma unroll
  for (int i = 0; i < 4; ++i) {
    u32 b0 = (u32)(__float2int_rn(v[i * 4 + 0] * scale) & 0xff);
    u32 b1 = (u32)(__float2int_rn(v[i * 4 + 1] * scale) & 0xff);
    u32 b2 = (u32)(__float2int_rn(v[i * 4 + 2] * scale) & 0xff);
    u32 b3 = (u32)(__float2int_rn(v[i * 4 + 3] * scale) & 0xff);
    pk[i] = b0 | (b1 << 8) | (b2 << 16) | (b3 << 24);
  }
  *(uint4*)(out + (size_t)row * 1024 + lane * 16) = make_uint4(pk[0], pk[1], pk[2], pk[3]);
  if (lane == 0) sc[row] = mx > 0.f ? mx / 127.f : 0.f;
}

// ---------------------------------------------------------------------------
// h row (1024) per wave: h = relu(x*W+b), per-row max, quantize to i8 [0,127]
__global__ __launch_bounds__(256) void hgen_i8(const float* __restrict__ x,
                                               const float* __restrict__ W,
                                               const float* __restrict__ bias,
                                               u8* __restrict__ h, float* __restrict__ hsc,
                                               int F, int logF, int b0, int xstride) {
  const int row  = blockIdx.x * 4 + (threadIdx.x >> 6);
  const int lane = threadIdx.x & 63;
  const int f = row & (F - 1);
  const int b = b0 + (row >> logF);
  const float xv = x[(size_t)b * xstride + f];
  const float4* wp = (const float4*)(W + (size_t)f * 1024 + lane * 16);
  const float4* bp = (const float4*)(bias + (size_t)f * 1024 + lane * 16);
  float hv[16];
  float mx = 0.f;
#pragma unroll
  for (int i = 0; i < 4; ++i) {
    float4 wv = wp[i];
    float4 bv = bp[i];
    hv[i * 4 + 0] = fmaxf(xv * wv.x + bv.x, 0.f);
    hv[i * 4 + 1] = fmaxf(xv * wv.y + bv.y, 0.f);
    hv[i * 4 + 2] = fmaxf(xv * wv.z + bv.z, 0.f);
    hv[i * 4 + 3] = fmaxf(xv * wv.w + bv.w, 0.f);
#pragma unroll
    for (int j = 0; j < 4; ++j) mx = fmaxf(mx, hv[i * 4 + j]);
  }
#pragma unroll
  for (int m = 1; m < 64; m <<= 1) mx = fmaxf(mx, __shfl_xor(mx, m));
  const float scale = mx > 0.f ? 127.f / mx : 0.f;
  u32 pk[4];
#pragma unroll
  for (int i = 0; i < 4; ++i) {
    u32 q0 = (u32)__float2int_rn(hv[i * 4 + 0] * scale);
    u32 q1 = (u32)__float2int_rn(hv[i * 4 + 1] * scale);
    u32 q2 = (u32)__float2int_rn(hv[i * 4 + 2] * scale);
    u32 q3 = (u32)__float2int_rn(hv[i * 4 + 3] * scale);
    pk[i] = q0 | (q1 << 8) | (q2 << 16) | (q3 << 24);
  }
  *(uint4*)(h + (size_t)row * 1024 + lane * 16) = make_uint4(pk[0], pk[1], pk[2], pk[3]);
  if (lane == 0) hsc[row] = mx > 0.f ? mx / 127.f : 0.f;
}

// ---------------------------------------------------------------------------
// i8 GEMM, byte-identical geometry to the proven bf16 gemm_ph:
// C(MxN,bf16) = sA[m]*sB[n]*(qA(MxK,i8) . qB^T(NxK,i8)) + bias(N)
// 256x128 tile, BK=64 BYTES (=64 i8 = one 16x16x64 MFMA K), 8 waves 4Mx2N,
// triple-buffered (72 KB -> 2 blocks/CU), counted vmcnt(3), NT=K/64 (=16:
// half the barriers of the bf16 version). Requires M%256, N%128, K%64, NT>=2.
__global__ __launch_bounds__(512, 4) void gemm_i8(const u8* __restrict__ A,
                                                  const u8* __restrict__ B,
                                                  const float* __restrict__ sAsc,
                                                  const float* __restrict__ sBsc,
                                                  const float* __restrict__ bias,
                                                  u16* __restrict__ C,
                                                  int M, int N, int K) {
  __shared__ u8 sA[3][256 * 64];   // 3 x 16 KB, chunk = 16 rows x 64 B
  __shared__ u8 sB[3][128 * 64];   // 3 x  8 KB
  const int tid  = threadIdx.x;
  const int lane = tid & 63;
  const int w    = tid >> 6;
  const int wm   = w >> 1;          // 0..3 : 64-row group
  const int wn   = w & 1;           // 0..1 : 64-col group

  const int nwg = gridDim.x * gridDim.y;
  const int wg  = blockIdx.y * gridDim.x + blockIdx.x;
  const int swz = xcd_swz(wg, nwg);
  const int n0 = (swz % gridDim.x) * 128;
  const int m0 = (swz / gridDim.x) * 256;

  i32x4 acc[4][4] = {};

  const int r_in  = lane >> 2;                       // 0..15 row within chunk
  const int s_src = (lane & 3) ^ ((lane >> 3) & 3);  // 16B slot of 4, pre-swizzled

  auto stage = [&](int kt, int b) {
    const int k0 = kt << 6;   // 64 bytes per K-tile
    gload16(A + (size_t)(m0 + w * 16 + r_in) * K + k0 + s_src * 16, &sA[b][w * 1024]);
    gload16(A + (size_t)(m0 + (w + 8) * 16 + r_in) * K + k0 + s_src * 16, &sA[b][(w + 8) * 1024]);
    gload16(B + (size_t)(n0 + w * 16 + r_in) * K + k0 + s_src * 16, &sB[b][w * 1024]);
  };

  const int NT = K >> 6;
  stage(0, 0);
  stage(1, 1);
  asm volatile("s_waitcnt vmcnt(3)" ::: "memory");
  __builtin_amdgcn_s_barrier();

  int cur = 0, nx = 2;
  for (int t = 0; t < NT; ++t) {
    const bool more = (t + 2 < NT);
    if (more) stage(t + 2, nx);

    i32x4 af[4], bg[4];
    const int g = lane >> 4;         // 16B k-slot 0..3
#pragma unroll
    for (int mf = 0; mf < 4; ++mf) {
      int ra = wm * 64 + mf * 16 + (lane & 15);
      af[mf] = *(const i32x4*)(&sA[cur][ra * 64 + ((g ^ ((ra >> 1) & 3)) * 16)]);
    }
#pragma unroll
    for (int nf = 0; nf < 4; ++nf) {
      int rb = wn * 64 + nf * 16 + (lane & 15);
      bg[nf] = *(const i32x4*)(&sB[cur][rb * 64 + ((g ^ ((rb >> 1) & 3)) * 16)]);
    }
    asm volatile("s_waitcnt lgkmcnt(0)" ::: "memory");
    __builtin_amdgcn_sched_barrier(0);
    __builtin_amdgcn_s_setprio(1);
#pragma unroll
    for (int mf = 0; mf < 4; ++mf)
#pragma unroll
      for (int nf = 0; nf < 4; ++nf)
        mfma_i8(acc[mf][nf], af[mf], bg[nf]);
    __builtin_amdgcn_s_setprio(0);
    if (more) asm volatile("s_waitcnt vmcnt(3)" ::: "memory");
    else      asm volatile("s_waitcnt vmcnt(0)" ::: "memory");
    __builtin_amdgcn_s_barrier();
    cur = (cur == 2) ? 0 : cur + 1;
    nx  = (nx  == 2) ? 0 : nx  + 1;
  }

  // epilogue: D layout col = lane&15, row = (lane>>4)*4 + reg; de-scale rank-1
#pragma unroll
  for (int nf = 0; nf < 4; ++nf) {
    int cl = n0 + wn * 64 + nf * 16 + (lane & 15);
    float sb  = sBsc[cl];
    float bsv = bias[cl];
#pragma unroll
    for (int mf = 0; mf < 4; ++mf) {
      int r0 = m0 + wm * 64 + mf * 16 + (lane >> 4) * 4;
      float4 sa4 = *(const float4*)(sAsc + r0);
      const float* sap = (const float*)&sa4;
#pragma unroll
      for (int reg = 0; reg < 4; ++reg)
        C[(size_t)(r0 + reg) * N + cl] =
            f2bf((float)acc[mf][nf][reg] * (sap[reg] * sb) + bsv);
    }
  }
}

// ---------------------------------------------------------------------------
// 2-phase bf16 GEMM (866 TF): 256x128, BK=32, triple-buffer, counted vmcnt — out-proj.
__global__ __launch_bounds__(512, 4) void gemm_ph(const u16* __restrict__ A,
                                                  const u16* __restrict__ B,
                                                  const float* __restrict__ bias,
                                                  u16* __restrict__ C,
                                                  int M, int N, int K) {
  __shared__ u16 sA[3][256 * 32];
  __shared__ u16 sB[3][128 * 32];
  const int tid  = threadIdx.x;
  const int lane = tid & 63;
  const int w    = tid >> 6;
  const int wm   = w >> 1;
  const int wn   = w & 1;

  const int nwg = gridDim.x * gridDim.y;
  const int wg  = blockIdx.y * gridDim.x + blockIdx.x;
  const int swz = xcd_swz(wg, nwg);
  const int n0 = (swz % gridDim.x) * 128;
  const int m0 = (swz / gridDim.x) * 256;

  f32x4 acc[4][4] = {};

  const int r_in  = lane >> 2;
  const int s_src = (lane & 3) ^ ((lane >> 3) & 3);

  auto stage = [&](int kt, int b) {
    const int k0 = kt << 5;
    gload16(A + (size_t)(m0 + w * 16 + r_in) * K + k0 + s_src * 8, &sA[b][w * 512]);
    gload16(A + (size_t)(m0 + (w + 8) * 16 + r_in) * K + k0 + s_src * 8, &sA[b][(w + 8) * 512]);
    gload16(B + (size_t)(n0 + w * 16 + r_in) * K + k0 + s_src * 8, &sB[b][w * 512]);
  };

  const int NT = K >> 5;
  stage(0, 0);
  stage(1, 1);
  asm volatile("s_waitcnt vmcnt(3)" ::: "memory");
  __builtin_amdgcn_s_barrier();

  int cur = 0, nx = 2;
  for (int t = 0; t < NT; ++t) {
    const bool more = (t + 2 < NT);
    if (more) stage(t + 2, nx);

    bf16x8 af[4], bg[4];
    const int g = lane >> 4;
#pragma unroll
    for (int mf = 0; mf < 4; ++mf) {
      int ra = wm * 64 + mf * 16 + (lane & 15);
      af[mf] = *(const bf16x8*)(&sA[cur][ra * 32 + ((g ^ ((ra >> 1) & 3)) * 8)]);
    }
#pragma unroll
    for (int nf = 0; nf < 4; ++nf) {
      int rb = wn * 64 + nf * 16 + (lane & 15);
      bg[nf] = *(const bf16x8*)(&sB[cur][rb * 32 + ((g ^ ((rb >> 1) & 3)) * 8)]);
    }
    asm volatile("s_waitcnt lgkmcnt(0)" ::: "memory");
    __builtin_amdgcn_sched_barrier(0);
    __builtin_amdgcn_s_setprio(1);
#pragma unroll
    for (int mf = 0; mf < 4; ++mf)
#pragma unroll
      for (int nf = 0; nf < 4; ++nf)
        acc[mf][nf] = __builtin_amdgcn_mfma_f32_16x16x32_bf16(af[mf], bg[nf], acc[mf][nf], 0, 0, 0);
    __builtin_amdgcn_s_setprio(0);
    if (more) asm volatile("s_waitcnt vmcnt(3)" ::: "memory");
    else      asm volatile("s_waitcnt vmcnt(0)" ::: "memory");
    __builtin_amdgcn_s_barrier();
    cur = (cur == 2) ? 0 : cur + 1;
    nx  = (nx  == 2) ? 0 : nx  + 1;
  }

#pragma unroll
  for (int nf = 0; nf < 4; ++nf) {
    int cl = n0 + wn * 64 + nf * 16 + (lane & 15);
    float bsv = bias[cl];
#pragma unroll
    for (int mf = 0; mf < 4; ++mf) {
      int r0 = m0 + wm * 64 + mf * 16 + (lane >> 4) * 4;
#pragma unroll
      for (int reg = 0; reg < 4; ++reg)
        C[(size_t)(r0 + reg) * N + cl] = f2bf(acc[mf][nf][reg] + bsv);
    }
  }
}

// ---------------------------------------------------------------------------
// Fused attention, QBLK=128: 8 waves (512 thr), each wave owns 16 q-rows.
__global__ __launch_bounds__(512) void attn(const u16* __restrict__ qkv,
                                            u16* __restrict__ o_out, int F) {
  __shared__ u16 q_lds[128 * 136];   // [128][128+8]
  __shared__ u16 k_lds[64 * 136];
  __shared__ u16 vT[128 * 72];       // [128 d][64+8 kpos], col-swizzled
  __shared__ u16 p_lds[8 * 16 * 72]; // per-wave [16 qrow][64+8 kpos]

  const int tid  = threadIdx.x;
  const int lane = tid & 63;
  const int w    = tid >> 6;          // 0..7

  const int swzb = xcd_swz(blockIdx.x, gridDim.x);
  const int nqb  = F >> 7;
  const int qb   = swzb % nqb;
  const int head = (swzb / nqb) & 7;
  const int bc   = swzb / (nqb * 8);

  const size_t rowbase = (size_t)bc * F * 3072;
  const float scale = 0.08838834764831845f;   // 1/sqrt(128)

  {
    const u16* qsrc = qkv + rowbase + (size_t)(qb * 128) * 3072 + head * 128;
    for (int it = tid; it < 2048; it += 512) {
      int r = it >> 4, s = it & 15;
      bf16x8 v = *(const bf16x8*)(qsrc + (size_t)r * 3072 + s * 8);
      bf16x8 o;
#pragma unroll
      for (int j = 0; j < 8; ++j) o[j] = (short)f2bf(bf2f((u16)v[j]) * scale);
      *(bf16x8*)(q_lds + r * 136 + s * 8) = o;
    }
  }

  f32x4 o_acc[8] = {};
  float m_run = -INFINITY, l_run = 0.f;
  const int qr = lane & 15;
  const int g4 = lane >> 4;

  const int nkb = F >> 6;
  for (int kb = 0; kb < nkb; ++kb) {
    __syncthreads();
    const u16* ksrc = qkv + rowbase + (size_t)(kb * 64) * 3072 + 1024 + head * 128;
    const u16* vsrc = ksrc + 1024;
    for (int it = tid; it < 1024; it += 512) {
      int r = it >> 4, s = it & 15;
      *(bf16x8*)(k_lds + r * 136 + s * 8) = *(const bf16x8*)(ksrc + (size_t)r * 3072 + s * 8);
    }
    {
      int g2 = tid >> 4, s = tid & 15;
      const u16* v0 = vsrc + (size_t)(2 * g2) * 3072 + s * 8;
      bf16x8 a = *(const bf16x8*)(v0);
      bf16x8 b = *(const bf16x8*)(v0 + 3072);
      int rs0 = (2 * g2) ^ ((s & 7) << 3);
      int d0  = s * 8;
#pragma unroll
      for (int j = 0; j < 8; ++j) {
        u32 pk = (u32)(u16)a[j] | ((u32)(u16)b[j] << 16);
        *(u32*)(vT + (d0 + j) * 72 + rs0) = pk;
      }
    }
    __syncthreads();

    f32x4 sa[4] = {};
#pragma unroll
    for (int kk = 0; kk < 4; ++kk) {
      bf16x8 bq = *(const bf16x8*)(q_lds + (w * 16 + qr) * 136 + kk * 32 + 8 * g4);
#pragma unroll
      for (int f = 0; f < 4; ++f) {
        bf16x8 ak = *(const bf16x8*)(k_lds + (f * 16 + qr) * 136 + kk * 32 + 8 * g4);
        sa[f] = __builtin_amdgcn_mfma_f32_16x16x32_bf16(ak, bq, sa[f], 0, 0, 0);
      }
    }

    float tmax = -INFINITY;
#pragma unroll
    for (int f = 0; f < 4; ++f)
#pragma unroll
      for (int rr = 0; rr < 4; ++rr) tmax = fmaxf(tmax, sa[f][rr]);
    tmax = fmaxf(tmax, __shfl_xor(tmax, 16));
    tmax = fmaxf(tmax, __shfl_xor(tmax, 32));
    float mnew  = fmaxf(m_run, tmax);
    float alpha = __expf(m_run - mnew);
    float psum  = 0.f;
#pragma unroll
    for (int f = 0; f < 4; ++f) {
      u16 pp[4];
#pragma unroll
      for (int rr = 0; rr < 4; ++rr) {
        float p = __expf(sa[f][rr] - mnew);
        psum += p;
        pp[rr] = f2bf(p);
      }
      uint2 u;
      u.x = (u32)pp[0] | ((u32)pp[1] << 16);
      u.y = (u32)pp[2] | ((u32)pp[3] << 16);
      *(uint2*)(p_lds + w * 1152 + qr * 72 + f * 16 + g4 * 4) = u;
    }
    psum += __shfl_xor(psum, 16);
    psum += __shfl_xor(psum, 32);
    l_run = l_run * alpha + psum;
    m_run = mnew;

#pragma unroll
    for (int rr = 0; rr < 4; ++rr) {
      float ar = __shfl(alpha, g4 * 4 + rr);
#pragma unroll
      for (int g = 0; g < 8; ++g) o_acc[g][rr] *= ar;
    }

#pragma unroll
    for (int kk2 = 0; kk2 < 2; ++kk2) {
      bf16x8 pa = *(const bf16x8*)(p_lds + w * 1152 + qr * 72 + kk2 * 32 + 8 * g4);
#pragma unroll
      for (int g = 0; g < 8; ++g) {
        int swv = ((g * 2 + (qr >> 3)) & 7) << 3;
        bf16x8 vb = *(const bf16x8*)(vT + (g * 16 + qr) * 72 + ((kk2 * 32 + 8 * g4) ^ swv));
        o_acc[g] = __builtin_amdgcn_mfma_f32_16x16x32_bf16(pa, vb, o_acc[g], 0, 0, 0);
      }
    }
  }

  float linv = 1.f / l_run;
#pragma unroll
  for (int rr = 0; rr < 4; ++rr) {
    float lr = __shfl(linv, g4 * 4 + rr);
    size_t row = (size_t)bc * F + qb * 128 + w * 16 + g4 * 4 + rr;
#pragma unroll
    for (int g = 0; g < 8; ++g)
      o_out[row * 1024 + head * 128 + g * 16 + qr] = f2bf(o_acc[g][rr] * lr);
  }
}

// ---------------------------------------------------------------------------
__global__ __launch_bounds__(256) void ln_stats(const u16* __restrict__ proj,
                                                float2* __restrict__ stats) {
  int row  = blockIdx.x * 4 + (threadIdx.x >> 6);
  int lane = threadIdx.x & 63;
  const u16* p = proj + (size_t)row * 1024;
  float s = 0.f, s2 = 0.f;
#pragma unroll
  for (int i = 0; i < 2; ++i) {
    bf16x8 v = *(const bf16x8*)(p + (lane + i * 64) * 8);
#pragma unroll
    for (int j = 0; j < 8; ++j) { float f = bf2f((u16)v[j]); s += f; s2 += f * f; }
  }
#pragma unroll
  for (int m = 1; m < 64; m <<= 1) { s += __shfl_xor(s, m); s2 += __shfl_xor(s2, m); }
  if (lane == 0) {
    float mu  = s * (1.f / 1024.f);
    float var = s2 * (1.f / 1024.f) - mu * mu;
    stats[row] = make_float2(mu, rsqrtf(var + 1e-5f));
  }
}

__global__ __launch_bounds__(256) void ln_accum(const u16* __restrict__ proj,
                                                const float2* __restrict__ stats,
                                                const float* __restrict__ g,
                                                const float* __restrict__ beta,
                                                float* __restrict__ dp, int F, int b0) {
  int d  = blockIdx.x * 256 + threadIdx.x;
  int bc = blockIdx.z;
  int f0 = blockIdx.y * 64;
  const u16* base = proj + ((size_t)(bc * F + f0)) * 1024 + d;
  const float2* st = stats + bc * F + f0;
  float acc = 0.f;
  for (int f = 0; f < 64; ++f) {
    float2 s = st[f];
    acc += (bf2f(base[(size_t)f * 1024]) - s.x) * s.y;
  }
  acc = acc * g[d] + 64.f * beta[d];
  atomicAdd(&dp[(size_t)(b0 + bc) * 1024 + d], acc);
}

// ---------------------------------------------------------------------------
__global__ __launch_bounds__(256) void cosine_sig(const float* __restrict__ dp,
                                                  const float* __restrict__ tp,
                                                  float* __restrict__ out) {
  __shared__ float red[3][4];
  int b = blockIdx.x;
  int tid = threadIdx.x, lane = tid & 63, w = tid >> 6;
  float dot = 0.f, n1 = 0.f, n2 = 0.f;
  for (int i = tid; i < 1024; i += 256) {
    float a = dp[(size_t)b * 1024 + i], c = tp[(size_t)b * 1024 + i];
    dot += a * c; n1 += a * a; n2 += c * c;
  }
#pragma unroll
  for (int m = 1; m < 64; m <<= 1) {
    dot += __shfl_xor(dot, m); n1 += __shfl_xor(n1, m); n2 += __shfl_xor(n2, m);
  }
  if (lane == 0) { red[0][w] = dot; red[1][w] = n1; red[2][w] = n2; }
  __syncthreads();
  if (tid == 0) {
    dot = red[0][0] + red[0][1] + red[0][2] + red[0][3];
    n1  = red[1][0] + red[1][1] + red[1][2] + red[1][3];
    n2  = red[2][0] + red[2][1] + red[2][2] + red[2][3];
    float denom = fmaxf(sqrtf(n1) * sqrtf(n2), 1e-8f);
    out[b] = 1.f / (1.f + __expf(-dot / denom));
  }
}

// ---------------------------------------------------------------------------
extern "C" void kernel_launch(void* const* d_in, const int* in_sizes, int n_in,
                              void* d_out, int out_size, void* d_ws, size_t ws_size,
                              hipStream_t stream) {
  const float* drug   = (const float*)d_in[0];
  const float* target = (const float*)d_in[1];

  char* p = (char*)d_ws;
  auto alloc = [&](size_t bytes) -> char* {
    char* r = p; p += (bytes + 255) & ~(size_t)255; return r;
  };

  u8*    w8_d   = (u8*)alloc((size_t)3072 * 1024);
  float* wsc_d  = (float*)alloc((size_t)3072 * 4);
  u8*    w8_t   = (u8*)alloc((size_t)3072 * 1024);
  float* wsc_t  = (float*)alloc((size_t)3072 * 4);
  u16*   w_out_d = (u16*)alloc((size_t)1024 * 1024 * 2);
  u16*   w_out_t = (u16*)alloc((size_t)1024 * 1024 * 2);
  float* dp    = (float*)alloc((size_t)2 * 128 * 1024 * 4);
  float* tp    = dp + 128 * 1024;

  size_t fixed = (size_t)(p - (char*)d_ws);
  size_t per = (size_t)256 * 1024               /* h_i8 */
             + (size_t)256 * 4                  /* hsc */
             + (size_t)256 * 3072 * 2           /* qkv */
             + (size_t)256 * 1024 * 2 * 2       /* obuf + proj */
             + (size_t)256 * 8 + 4096;          /* stats + slack */
  int Bc = 8;
  if      (fixed + 128 * per <= ws_size) Bc = 128;
  else if (fixed +  64 * per <= ws_size) Bc = 64;
  else if (fixed +  32 * per <= ws_size) Bc = 32;
  else if (fixed +  16 * per <= ws_size) Bc = 16;

  u8*    h8     = (u8*)alloc((size_t)Bc * 256 * 1024);
  float* hsc    = (float*)alloc((size_t)Bc * 256 * 4);
  u16*   qkvbuf = (u16*)alloc((size_t)Bc * 256 * 3072 * 2);
  u16*   obuf   = (u16*)alloc((size_t)Bc * 256 * 1024 * 2);
  u16*   projbuf= (u16*)alloc((size_t)Bc * 256 * 1024 * 2);
  float2* statsb = (float2*)alloc((size_t)Bc * 256 * 8);

  cvt_w_i8<<<768, 256, 0, stream>>>((const float*)d_in[4],  w8_d, wsc_d);
  cvt_w_i8<<<768, 256, 0, stream>>>((const float*)d_in[12], w8_t, wsc_t);
  cvt_bf16<<<512, 256, 0, stream>>>((const float*)d_in[6],  w_out_d, 1024 * 128);
  cvt_bf16<<<512, 256, 0, stream>>>((const float*)d_in[14], w_out_t, 1024 * 128);
  hipMemsetAsync(dp, 0, (size_t)2 * 128 * 1024 * 4, stream);

  for (int br = 0; br < 2; ++br) {
    const int F = br ? 128 : 256, logF = br ? 7 : 8, xstride = br ? 1024 : 2048;
    const float* x    = br ? target : drug;
    const float* W    = (const float*)d_in[br ? 10 : 2];
    const float* Wb   = (const float*)d_in[br ? 11 : 3];
    u8*          w8   = br ? w8_t : w8_d;
    float*       wsc  = br ? wsc_t : wsc_d;
    const float* inb  = (const float*)d_in[br ? 13 : 5];
    u16*         wout = br ? w_out_t : w_out_d;
    const float* outb = (const float*)d_in[br ? 15 : 7];
    const float* gg   = (const float*)d_in[br ? 16 : 8];
    const float* bb   = (const float*)d_in[br ? 17 : 9];
    float*       accp = br ? tp : dp;

    const int nb = (br ? (2 * Bc > 128 ? 128 : 2 * Bc) : (Bc > 128 ? 128 : Bc));

    for (int b0 = 0; b0 < 128; b0 += nb) {
      const int Mr = nb * F;
      hgen_i8<<<Mr / 4, 256, 0, stream>>>(x, W, Wb, h8, hsc, F, logF, b0, xstride);
      gemm_i8<<<dim3(3072 / 128, Mr / 256), 512, 0, stream>>>(h8, w8, hsc, wsc, inb, qkvbuf, Mr, 3072, 1024);
      attn<<<(F / 128) * 8 * nb, 512, 0, stream>>>(qkvbuf, obuf, F);
      gemm_ph<<<dim3(1024 / 128, Mr / 256), 512, 0, stream>>>(obuf, wout, outb, projbuf, Mr, 1024, 1024);
      ln_stats<<<Mr / 4, 256, 0, stream>>>(projbuf, statsb);
      ln_accum<<<dim3(4, F / 64, nb), 256, 0, stream>>>(projbuf, statsb, gg, bb, accp, F, b0);
    }
  }
  cosine_sig<<<128, 256, 0, stream>>>(dp, tp, (float*)d_out);
}

// Round 11
// 579.703 us; speedup vs baseline: 1.6151x; 1.0676x over previous
//
#include <hip/hip_runtime.h>

typedef unsigned short u16;
typedef unsigned int   u32;
typedef unsigned char  u8;

using bf16x8 = __attribute__((ext_vector_type(8))) short;  // 8 bf16 in 4 VGPRs
using f32x4  = __attribute__((ext_vector_type(4))) float;
using i32x4  = __attribute__((ext_vector_type(4))) int;    // 16 i8 operand / i32 acc

__device__ __forceinline__ float bf2f(u16 h) {
  u32 u = ((u32)h) << 16;
  return __builtin_bit_cast(float, u);
}
__device__ __forceinline__ u16 f2bf(float f) {   // round-to-nearest-even
  u32 u = __builtin_bit_cast(u32, f);
  u += 0x7fffu + ((u >> 16) & 1u);
  return (u16)(u >> 16);
}

__device__ __forceinline__ void gload16(const void* src, void* ldsdst) {
  __builtin_amdgcn_global_load_lds(
      (const __attribute__((address_space(1))) void*)src,
      (__attribute__((address_space(3))) void*)ldsdst, 16, 0, 0);
}

// i8 MFMA via inline asm (ISA 10: v_mfma_i32_16x16x64_i8)
__device__ __forceinline__ void mfma_i8(i32x4& c, i32x4 a, i32x4 b) {
  asm volatile("v_mfma_i32_16x16x64_i8 %0, %1, %2, %0" : "+a"(c) : "v"(a), "v"(b));
}

// m204 bijective XCD swizzle
__device__ __forceinline__ int xcd_swz(int wg, int nwg) {
  int q = nwg >> 3, r = nwg & 7, xcd = wg & 7, loc = wg >> 3;
  return (xcd < r ? xcd * (q + 1) : r * (q + 1) + (xcd - r) * q) + loc;
}

// ---------------------------------------------------------------------------
// per-row (over K=1024) signed-i8 quantization of an f32 matrix (wave/row)
__global__ __launch_bounds__(256) void cvt_w_i8(const float* __restrict__ in,
                                                u8* __restrict__ out,
                                                float* __restrict__ sc) {
  const int row  = blockIdx.x * 4 + (threadIdx.x >> 6);
  const int lane = threadIdx.x & 63;
  const float4* p = (const float4*)(in + (size_t)row * 1024 + lane * 16);
  float v[16];
  float mx = 0.f;
#pragma unroll
  for (int i = 0; i < 4; ++i) {
    float4 t = p[i];
    v[i * 4 + 0] = t.x; v[i * 4 + 1] = t.y; v[i * 4 + 2] = t.z; v[i * 4 + 3] = t.w;
#pragma unroll
    for (int j = 0; j < 4; ++j) mx = fmaxf(mx, fabsf(v[i * 4 + j]));
  }
#pragma unroll
  for (int m = 1; m < 64; m <<= 1) mx = fmaxf(mx, __shfl_xor(mx, m));
  const float scale = mx > 0.f ? 127.f / mx : 0.f;
  u32 pk[4];
#pragma unroll
  for (int i = 0; i < 4; ++i) {
    u32 b0 = (u32)(__float2int_rn(v[i * 4 + 0] * scale) & 0xff);
    u32 b1 = (u32)(__float2int_rn(v[i * 4 + 1] * scale) & 0xff);
    u32 b2 = (u32)(__float2int_rn(v[i * 4 + 2] * scale) & 0xff);
    u32 b3 = (u32)(__float2int_rn(v[i * 4 + 3] * scale) & 0xff);
    pk[i] = b0 | (b1 << 8) | (b2 << 16) | (b3 << 24);
  }
  *(uint4*)(out + (size_t)row * 1024 + lane * 16) = make_uint4(pk[0], pk[1], pk[2], pk[3]);
  if (lane == 0) sc[row] = mx > 0.f ? mx / 127.f : 0.f;
}

// ---------------------------------------------------------------------------
// per-row signed-i8 quantization of a bf16 matrix (wave/row) — attn output
__global__ __launch_bounds__(256) void quant_i8(const u16* __restrict__ in,
                                                u8* __restrict__ out,
                                                float* __restrict__ sc) {
  const int row  = blockIdx.x * 4 + (threadIdx.x >> 6);
  const int lane = threadIdx.x & 63;
  const u16* p = in + (size_t)row * 1024 + lane * 16;
  float v[16];
  float mx = 0.f;
#pragma unroll
  for (int i = 0; i < 2; ++i) {
    bf16x8 t = *(const bf16x8*)(p + i * 8);
#pragma unroll
    for (int j = 0; j < 8; ++j) {
      float f = bf2f((u16)t[j]);
      v[i * 8 + j] = f;
      mx = fmaxf(mx, fabsf(f));
    }
  }
#pragma unroll
  for (int m = 1; m < 64; m <<= 1) mx = fmaxf(mx, __shfl_xor(mx, m));
  const float scale = mx > 0.f ? 127.f / mx : 0.f;
  u32 pk[4];
#pragma unroll
  for (int i = 0; i < 4; ++i) {
    u32 b0 = (u32)(__float2int_rn(v[i * 4 + 0] * scale) & 0xff);
    u32 b1 = (u32)(__float2int_rn(v[i * 4 + 1] * scale) & 0xff);
    u32 b2 = (u32)(__float2int_rn(v[i * 4 + 2] * scale) & 0xff);
    u32 b3 = (u32)(__float2int_rn(v[i * 4 + 3] * scale) & 0xff);
    pk[i] = b0 | (b1 << 8) | (b2 << 16) | (b3 << 24);
  }
  *(uint4*)(out + (size_t)row * 1024 + lane * 16) = make_uint4(pk[0], pk[1], pk[2], pk[3]);
  if (lane == 0) sc[row] = mx > 0.f ? mx / 127.f : 0.f;
}

// ---------------------------------------------------------------------------
// h row (1024) per wave: h = relu(x*W+b), per-row max, quantize to i8 [0,127]
__global__ __launch_bounds__(256) void hgen_i8(const float* __restrict__ x,
                                               const float* __restrict__ W,
                                               const float* __restrict__ bias,
                                               u8* __restrict__ h, float* __restrict__ hsc,
                                               int F, int logF, int b0, int xstride) {
  const int row  = blockIdx.x * 4 + (threadIdx.x >> 6);
  const int lane = threadIdx.x & 63;
  const int f = row & (F - 1);
  const int b = b0 + (row >> logF);
  const float xv = x[(size_t)b * xstride + f];
  const float4* wp = (const float4*)(W + (size_t)f * 1024 + lane * 16);
  const float4* bp = (const float4*)(bias + (size_t)f * 1024 + lane * 16);
  float hv[16];
  float mx = 0.f;
#pragma unroll
  for (int i = 0; i < 4; ++i) {
    float4 wv = wp[i];
    float4 bv = bp[i];
    hv[i * 4 + 0] = fmaxf(xv * wv.x + bv.x, 0.f);
    hv[i * 4 + 1] = fmaxf(xv * wv.y + bv.y, 0.f);
    hv[i * 4 + 2] = fmaxf(xv * wv.z + bv.z, 0.f);
    hv[i * 4 + 3] = fmaxf(xv * wv.w + bv.w, 0.f);
#pragma unroll
    for (int j = 0; j < 4; ++j) mx = fmaxf(mx, hv[i * 4 + j]);
  }
#pragma unroll
  for (int m = 1; m < 64; m <<= 1) mx = fmaxf(mx, __shfl_xor(mx, m));
  const float scale = mx > 0.f ? 127.f / mx : 0.f;
  u32 pk[4];
#pragma unroll
  for (int i = 0; i < 4; ++i) {
    u32 q0 = (u32)__float2int_rn(hv[i * 4 + 0] * scale);
    u32 q1 = (u32)__float2int_rn(hv[i * 4 + 1] * scale);
    u32 q2 = (u32)__float2int_rn(hv[i * 4 + 2] * scale);
    u32 q3 = (u32)__float2int_rn(hv[i * 4 + 3] * scale);
    pk[i] = q0 | (q1 << 8) | (q2 << 16) | (q3 << 24);
  }
  *(uint4*)(h + (size_t)row * 1024 + lane * 16) = make_uint4(pk[0], pk[1], pk[2], pk[3]);
  if (lane == 0) hsc[row] = mx > 0.f ? mx / 127.f : 0.f;
}

// ---------------------------------------------------------------------------
// i8 GEMM: C(MxN,bf16) = sA[m]*sB[n]*(qA . qB^T) + bias(N)
// 256x128 tile, BK=64 i8, 8 waves 4Mx2N, triple-buffered, counted vmcnt(3).
// Requires M%256, N%128, K%64, K/64>=2.
__global__ __launch_bounds__(512, 4) void gemm_i8(const u8* __restrict__ A,
                                                  const u8* __restrict__ B,
                                                  const float* __restrict__ sAsc,
                                                  const float* __restrict__ sBsc,
                                                  const float* __restrict__ bias,
                                                  u16* __restrict__ C,
                                                  int M, int N, int K) {
  __shared__ u8 sA[3][256 * 64];
  __shared__ u8 sB[3][128 * 64];
  const int tid  = threadIdx.x;
  const int lane = tid & 63;
  const int w    = tid >> 6;
  const int wm   = w >> 1;
  const int wn   = w & 1;

  const int nwg = gridDim.x * gridDim.y;
  const int wg  = blockIdx.y * gridDim.x + blockIdx.x;
  const int swz = xcd_swz(wg, nwg);
  const int n0 = (swz % gridDim.x) * 128;
  const int m0 = (swz / gridDim.x) * 256;

  i32x4 acc[4][4] = {};

  const int r_in  = lane >> 2;
  const int s_src = (lane & 3) ^ ((lane >> 3) & 3);

  auto stage = [&](int kt, int b) {
    const int k0 = kt << 6;
    gload16(A + (size_t)(m0 + w * 16 + r_in) * K + k0 + s_src * 16, &sA[b][w * 1024]);
    gload16(A + (size_t)(m0 + (w + 8) * 16 + r_in) * K + k0 + s_src * 16, &sA[b][(w + 8) * 1024]);
    gload16(B + (size_t)(n0 + w * 16 + r_in) * K + k0 + s_src * 16, &sB[b][w * 1024]);
  };

  const int NT = K >> 6;
  stage(0, 0);
  stage(1, 1);
  asm volatile("s_waitcnt vmcnt(3)" ::: "memory");
  __builtin_amdgcn_s_barrier();

  int cur = 0, nx = 2;
  for (int t = 0; t < NT; ++t) {
    const bool more = (t + 2 < NT);
    if (more) stage(t + 2, nx);

    i32x4 af[4], bg[4];
    const int g = lane >> 4;
#pragma unroll
    for (int mf = 0; mf < 4; ++mf) {
      int ra = wm * 64 + mf * 16 + (lane & 15);
      af[mf] = *(const i32x4*)(&sA[cur][ra * 64 + ((g ^ ((ra >> 1) & 3)) * 16)]);
    }
#pragma unroll
    for (int nf = 0; nf < 4; ++nf) {
      int rb = wn * 64 + nf * 16 + (lane & 15);
      bg[nf] = *(const i32x4*)(&sB[cur][rb * 64 + ((g ^ ((rb >> 1) & 3)) * 16)]);
    }
    asm volatile("s_waitcnt lgkmcnt(0)" ::: "memory");
    __builtin_amdgcn_sched_barrier(0);
    __builtin_amdgcn_s_setprio(1);
#pragma unroll
    for (int mf = 0; mf < 4; ++mf)
#pragma unroll
      for (int nf = 0; nf < 4; ++nf)
        mfma_i8(acc[mf][nf], af[mf], bg[nf]);
    __builtin_amdgcn_s_setprio(0);
    if (more) asm volatile("s_waitcnt vmcnt(3)" ::: "memory");
    else      asm volatile("s_waitcnt vmcnt(0)" ::: "memory");
    __builtin_amdgcn_s_barrier();
    cur = (cur == 2) ? 0 : cur + 1;
    nx  = (nx  == 2) ? 0 : nx  + 1;
  }

#pragma unroll
  for (int nf = 0; nf < 4; ++nf) {
    int cl = n0 + wn * 64 + nf * 16 + (lane & 15);
    float sb  = sBsc[cl];
    float bsv = bias[cl];
#pragma unroll
    for (int mf = 0; mf < 4; ++mf) {
      int r0 = m0 + wm * 64 + mf * 16 + (lane >> 4) * 4;
      float4 sa4 = *(const float4*)(sAsc + r0);
      const float* sap = (const float*)&sa4;
#pragma unroll
      for (int reg = 0; reg < 4; ++reg)
        C[(size_t)(r0 + reg) * N + cl] =
            f2bf((float)acc[mf][nf][reg] * (sap[reg] * sb) + bsv);
    }
  }
}

// ---------------------------------------------------------------------------
// Fused attention, QBLK=128, 8 waves: Q IN REGISTERS (no q_lds).
// Each wave owns 16 q-rows; per-lane QK^T B-fragment = 4x bf16x8 (reused
// across all K-tiles). LDS = K + vT + P = 54 KB -> 2 blocks/CU (16 waves).
__global__ __launch_bounds__(512, 4) void attn(const u16* __restrict__ qkv,
                                               u16* __restrict__ o_out, int F) {
  __shared__ u16 k_lds[64 * 136];
  __shared__ u16 vT[128 * 72];       // [128 d][64+8 kpos], col-swizzled
  __shared__ u16 p_lds[8 * 16 * 72]; // per-wave [16 qrow][64+8 kpos]

  const int tid  = threadIdx.x;
  const int lane = tid & 63;
  const int w    = tid >> 6;          // 0..7

  const int swzb = xcd_swz(blockIdx.x, gridDim.x);
  const int nqb  = F >> 7;
  const int qb   = swzb % nqb;
  const int head = (swzb / nqb) & 7;
  const int bc   = swzb / (nqb * 8);

  const size_t rowbase = (size_t)bc * F * 3072;
  const float scale = 0.08838834764831845f;   // 1/sqrt(128)

  const int qr = lane & 15;
  const int g4 = lane >> 4;

  // Q fragments in registers: row (qb*128 + w*16 + qr), 16B slices kk*32+8*g4
  bf16x8 qreg[4];
  {
    const u16* qsrc = qkv + rowbase +
                      (size_t)(qb * 128 + w * 16 + qr) * 3072 + head * 128;
#pragma unroll
    for (int kk = 0; kk < 4; ++kk) {
      bf16x8 v = *(const bf16x8*)(qsrc + kk * 32 + 8 * g4);
#pragma unroll
      for (int j = 0; j < 8; ++j) v[j] = (short)f2bf(bf2f((u16)v[j]) * scale);
      qreg[kk] = v;
    }
  }

  f32x4 o_acc[8] = {};
  float m_run = -INFINITY, l_run = 0.f;

  const int nkb = F >> 6;
  for (int kb = 0; kb < nkb; ++kb) {
    __syncthreads();   // prev compute done with k_lds/vT
    const u16* ksrc = qkv + rowbase + (size_t)(kb * 64) * 3072 + 1024 + head * 128;
    const u16* vsrc = ksrc + 1024;
    for (int it = tid; it < 1024; it += 512) {
      int r = it >> 4, s = it & 15;
      *(bf16x8*)(k_lds + r * 136 + s * 8) = *(const bf16x8*)(ksrc + (size_t)r * 3072 + s * 8);
    }
    {
      int g2 = tid >> 4, s = tid & 15;
      const u16* v0 = vsrc + (size_t)(2 * g2) * 3072 + s * 8;
      bf16x8 a = *(const bf16x8*)(v0);
      bf16x8 b = *(const bf16x8*)(v0 + 3072);
      int rs0 = (2 * g2) ^ ((s & 7) << 3);
      int d0  = s * 8;
#pragma unroll
      for (int j = 0; j < 8; ++j) {
        u32 pk = (u32)(u16)a[j] | ((u32)(u16)b[j] << 16);
        *(u32*)(vT + (d0 + j) * 72 + rs0) = pk;
      }
    }
    __syncthreads();

    // S^T (64 kpos x 16 qrows): A = k rows, B = q^T (registers)
    f32x4 sa[4] = {};
#pragma unroll
    for (int kk = 0; kk < 4; ++kk) {
#pragma unroll
      for (int f = 0; f < 4; ++f) {
        bf16x8 ak = *(const bf16x8*)(k_lds + (f * 16 + qr) * 136 + kk * 32 + 8 * g4);
        sa[f] = __builtin_amdgcn_mfma_f32_16x16x32_bf16(ak, qreg[kk], sa[f], 0, 0, 0);
      }
    }

    float tmax = -INFINITY;
#pragma unroll
    for (int f = 0; f < 4; ++f)
#pragma unroll
      for (int rr = 0; rr < 4; ++rr) tmax = fmaxf(tmax, sa[f][rr]);
    tmax = fmaxf(tmax, __shfl_xor(tmax, 16));
    tmax = fmaxf(tmax, __shfl_xor(tmax, 32));
    float mnew  = fmaxf(m_run, tmax);
    float alpha = __expf(m_run - mnew);
    float psum  = 0.f;
#pragma unroll
    for (int f = 0; f < 4; ++f) {
      u16 pp[4];
#pragma unroll
      for (int rr = 0; rr < 4; ++rr) {
        float p = __expf(sa[f][rr] - mnew);
        psum += p;
        pp[rr] = f2bf(p);
      }
      uint2 u;
      u.x = (u32)pp[0] | ((u32)pp[1] << 16);
      u.y = (u32)pp[2] | ((u32)pp[3] << 16);
      *(uint2*)(p_lds + w * 1152 + qr * 72 + f * 16 + g4 * 4) = u;
    }
    psum += __shfl_xor(psum, 16);
    psum += __shfl_xor(psum, 32);
    l_run = l_run * alpha + psum;
    m_run = mnew;

#pragma unroll
    for (int rr = 0; rr < 4; ++rr) {
      float ar = __shfl(alpha, g4 * 4 + rr);
#pragma unroll
      for (int g = 0; g < 8; ++g) o_acc[g][rr] *= ar;
    }

#pragma unroll
    for (int kk2 = 0; kk2 < 2; ++kk2) {
      bf16x8 pa = *(const bf16x8*)(p_lds + w * 1152 + qr * 72 + kk2 * 32 + 8 * g4);
#pragma unroll
      for (int g = 0; g < 8; ++g) {
        int swv = ((g * 2 + (qr >> 3)) & 7) << 3;
        bf16x8 vb = *(const bf16x8*)(vT + (g * 16 + qr) * 72 + ((kk2 * 32 + 8 * g4) ^ swv));
        o_acc[g] = __builtin_amdgcn_mfma_f32_16x16x32_bf16(pa, vb, o_acc[g], 0, 0, 0);
      }
    }
  }

  float linv = 1.f / l_run;
#pragma unroll
  for (int rr = 0; rr < 4; ++rr) {
    float lr = __shfl(linv, g4 * 4 + rr);
    size_t row = (size_t)bc * F + qb * 128 + w * 16 + g4 * 4 + rr;
#pragma unroll
    for (int g = 0; g < 8; ++g)
      o_out[row * 1024 + head * 128 + g * 16 + qr] = f2bf(o_acc[g][rr] * lr);
  }
}

// ---------------------------------------------------------------------------
__global__ __launch_bounds__(256) void ln_stats(const u16* __restrict__ proj,
                                                float2* __restrict__ stats) {
  int row  = blockIdx.x * 4 + (threadIdx.x >> 6);
  int lane = threadIdx.x & 63;
  const u16* p = proj + (size_t)row * 1024;
  float s = 0.f, s2 = 0.f;
#pragma unroll
  for (int i = 0; i < 2; ++i) {
    bf16x8 v = *(const bf16x8*)(p + (lane + i * 64) * 8);
#pragma unroll
    for (int j = 0; j < 8; ++j) { float f = bf2f((u16)v[j]); s += f; s2 += f * f; }
  }
#pragma unroll
  for (int m = 1; m < 64; m <<= 1) { s += __shfl_xor(s, m); s2 += __shfl_xor(s2, m); }
  if (lane == 0) {
    float mu  = s * (1.f / 1024.f);
    float var = s2 * (1.f / 1024.f) - mu * mu;
    stats[row] = make_float2(mu, rsqrtf(var + 1e-5f));
  }
}

__global__ __launch_bounds__(256) void ln_accum(const u16* __restrict__ proj,
                                                const float2* __restrict__ stats,
                                                const float* __restrict__ g,
                                                const float* __restrict__ beta,
                                                float* __restrict__ dp, int F, int b0) {
  int d  = blockIdx.x * 256 + threadIdx.x;
  int bc = blockIdx.z;
  int f0 = blockIdx.y * 64;
  const u16* base = proj + ((size_t)(bc * F + f0)) * 1024 + d;
  const float2* st = stats + bc * F + f0;
  float acc = 0.f;
  for (int f = 0; f < 64; ++f) {
    float2 s = st[f];
    acc += (bf2f(base[(size_t)f * 1024]) - s.x) * s.y;
  }
  acc = acc * g[d] + 64.f * beta[d];
  atomicAdd(&dp[(size_t)(b0 + bc) * 1024 + d], acc);
}

// ---------------------------------------------------------------------------
__global__ __launch_bounds__(256) void cosine_sig(const float* __restrict__ dp,
                                                  const float* __restrict__ tp,
                                                  float* __restrict__ out) {
  __shared__ float red[3][4];
  int b = blockIdx.x;
  int tid = threadIdx.x, lane = tid & 63, w = tid >> 6;
  float dot = 0.f, n1 = 0.f, n2 = 0.f;
  for (int i = tid; i < 1024; i += 256) {
    float a = dp[(size_t)b * 1024 + i], c = tp[(size_t)b * 1024 + i];
    dot += a * c; n1 += a * a; n2 += c * c;
  }
#pragma unroll
  for (int m = 1; m < 64; m <<= 1) {
    dot += __shfl_xor(dot, m); n1 += __shfl_xor(n1, m); n2 += __shfl_xor(n2, m);
  }
  if (lane == 0) { red[0][w] = dot; red[1][w] = n1; red[2][w] = n2; }
  __syncthreads();
  if (tid == 0) {
    dot = red[0][0] + red[0][1] + red[0][2] + red[0][3];
    n1  = red[1][0] + red[1][1] + red[1][2] + red[1][3];
    n2  = red[2][0] + red[2][1] + red[2][2] + red[2][3];
    float denom = fmaxf(sqrtf(n1) * sqrtf(n2), 1e-8f);
    out[b] = 1.f / (1.f + __expf(-dot / denom));
  }
}

// ---------------------------------------------------------------------------
extern "C" void kernel_launch(void* const* d_in, const int* in_sizes, int n_in,
                              void* d_out, int out_size, void* d_ws, size_t ws_size,
                              hipStream_t stream) {
  const float* drug   = (const float*)d_in[0];
  const float* target = (const float*)d_in[1];

  char* p = (char*)d_ws;
  auto alloc = [&](size_t bytes) -> char* {
    char* r = p; p += (bytes + 255) & ~(size_t)255; return r;
  };

  u8*    w8_d    = (u8*)alloc((size_t)3072 * 1024);
  float* wsc_d   = (float*)alloc((size_t)3072 * 4);
  u8*    w8_t    = (u8*)alloc((size_t)3072 * 1024);
  float* wsc_t   = (float*)alloc((size_t)3072 * 4);
  u8*    w8o_d   = (u8*)alloc((size_t)1024 * 1024);
  float* wsco_d  = (float*)alloc((size_t)1024 * 4);
  u8*    w8o_t   = (u8*)alloc((size_t)1024 * 1024);
  float* wsco_t  = (float*)alloc((size_t)1024 * 4);
  float* dp      = (float*)alloc((size_t)2 * 128 * 1024 * 4);
  float* tp      = dp + 128 * 1024;

  size_t fixed = (size_t)(p - (char*)d_ws);
  size_t per = (size_t)256 * 1024               /* h_i8 (reused as o_i8) */
             + (size_t)256 * 4                  /* hsc (reused as osc) */
             + (size_t)256 * 3072 * 2           /* qkv */
             + (size_t)256 * 1024 * 2 * 2       /* obuf + proj */
             + (size_t)256 * 8 + 4096;          /* stats + slack */
  int Bc = 8;
  if      (fixed + 128 * per <= ws_size) Bc = 128;
  else if (fixed +  64 * per <= ws_size) Bc = 64;
  else if (fixed +  32 * per <= ws_size) Bc = 32;
  else if (fixed +  16 * per <= ws_size) Bc = 16;

  u8*    h8     = (u8*)alloc((size_t)Bc * 256 * 1024);   // also o_i8 after qkv
  float* hsc    = (float*)alloc((size_t)Bc * 256 * 4);   // also osc
  u16*   qkvbuf = (u16*)alloc((size_t)Bc * 256 * 3072 * 2);
  u16*   obuf   = (u16*)alloc((size_t)Bc * 256 * 1024 * 2);
  u16*   projbuf= (u16*)alloc((size_t)Bc * 256 * 1024 * 2);
  float2* statsb = (float2*)alloc((size_t)Bc * 256 * 8);

  cvt_w_i8<<<768, 256, 0, stream>>>((const float*)d_in[4],  w8_d, wsc_d);
  cvt_w_i8<<<768, 256, 0, stream>>>((const float*)d_in[12], w8_t, wsc_t);
  cvt_w_i8<<<256, 256, 0, stream>>>((const float*)d_in[6],  w8o_d, wsco_d);
  cvt_w_i8<<<256, 256, 0, stream>>>((const float*)d_in[14], w8o_t, wsco_t);
  hipMemsetAsync(dp, 0, (size_t)2 * 128 * 1024 * 4, stream);

  for (int br = 0; br < 2; ++br) {
    const int F = br ? 128 : 256, logF = br ? 7 : 8, xstride = br ? 1024 : 2048;
    const float* x    = br ? target : drug;
    const float* W    = (const float*)d_in[br ? 10 : 2];
    const float* Wb   = (const float*)d_in[br ? 11 : 3];
    u8*          w8   = br ? w8_t : w8_d;
    float*       wsc  = br ? wsc_t : wsc_d;
    const float* inb  = (const float*)d_in[br ? 13 : 5];
    u8*          w8o  = br ? w8o_t : w8o_d;
    float*       wsco = br ? wsco_t : wsco_d;
    const float* outb = (const float*)d_in[br ? 15 : 7];
    const float* gg   = (const float*)d_in[br ? 16 : 8];
    const float* bb   = (const float*)d_in[br ? 17 : 9];
    float*       accp = br ? tp : dp;

    const int nb = (br ? (2 * Bc > 128 ? 128 : 2 * Bc) : (Bc > 128 ? 128 : Bc));

    for (int b0 = 0; b0 < 128; b0 += nb) {
      const int Mr = nb * F;
      hgen_i8<<<Mr / 4, 256, 0, stream>>>(x, W, Wb, h8, hsc, F, logF, b0, xstride);
      gemm_i8<<<dim3(3072 / 128, Mr / 256), 512, 0, stream>>>(h8, w8, hsc, wsc, inb, qkvbuf, Mr, 3072, 1024);
      attn<<<(F / 128) * 8 * nb, 512, 0, stream>>>(qkvbuf, obuf, F);
      quant_i8<<<Mr / 4, 256, 0, stream>>>(obuf, h8, hsc);   // h8/hsc reused as o8/osc
      gemm_i8<<<dim3(1024 / 128, Mr / 256), 512, 0, stream>>>(h8, w8o, hsc, wsco, outb, projbuf, Mr, 1024, 1024);
      ln_stats<<<Mr / 4, 256, 0, stream>>>(projbuf, statsb);
      ln_accum<<<dim3(4, F / 64, nb), 256, 0, stream>>>(projbuf, statsb, gg, bb, accp, F, b0);
    }
  }
  cosine_sig<<<128, 256, 0, stream>>>(dp, tp, (float*)d_out);
}

// Round 12
// 532.067 us; speedup vs baseline: 1.7597x; 1.0895x over previous
//
#include <hip/hip_runtime.h>

typedef unsigned short u16;
typedef unsigned int   u32;
typedef unsigned char  u8;

using bf16x8 = __attribute__((ext_vector_type(8))) short;  // 8 bf16 in 4 VGPRs
using f32x4  = __attribute__((ext_vector_type(4))) float;
using i32x4  = __attribute__((ext_vector_type(4))) int;    // 16 i8 operand / i32 acc

__device__ __forceinline__ float bf2f(u16 h) {
  u32 u = ((u32)h) << 16;
  return __builtin_bit_cast(float, u);
}
__device__ __forceinline__ u16 f2bf(float f) {   // round-to-nearest-even
  u32 u = __builtin_bit_cast(u32, f);
  u += 0x7fffu + ((u >> 16) & 1u);
  return (u16)(u >> 16);
}

__device__ __forceinline__ void gload16(const void* src, void* ldsdst) {
  __builtin_amdgcn_global_load_lds(
      (const __attribute__((address_space(1))) void*)src,
      (__attribute__((address_space(3))) void*)ldsdst, 16, 0, 0);
}

// i8 MFMA via inline asm (ISA 10: v_mfma_i32_16x16x64_i8)
__device__ __forceinline__ void mfma_i8(i32x4& c, i32x4 a, i32x4 b) {
  asm volatile("v_mfma_i32_16x16x64_i8 %0, %1, %2, %0" : "+a"(c) : "v"(a), "v"(b));
}

// m204 bijective XCD swizzle
__device__ __forceinline__ int xcd_swz(int wg, int nwg) {
  int q = nwg >> 3, r = nwg & 7, xcd = wg & 7, loc = wg >> 3;
  return (xcd < r ? xcd * (q + 1) : r * (q + 1) + (xcd - r) * q) + loc;
}

// ---------------------------------------------------------------------------
// per-row (over K=1024) signed-i8 quantization of an f32 matrix (wave/row)
__global__ __launch_bounds__(256) void cvt_w_i8(const float* __restrict__ in,
                                                u8* __restrict__ out,
                                                float* __restrict__ sc) {
  const int row  = blockIdx.x * 4 + (threadIdx.x >> 6);
  const int lane = threadIdx.x & 63;
  const float4* p = (const float4*)(in + (size_t)row * 1024 + lane * 16);
  float v[16];
  float mx = 0.f;
#pragma unroll
  for (int i = 0; i < 4; ++i) {
    float4 t = p[i];
    v[i * 4 + 0] = t.x; v[i * 4 + 1] = t.y; v[i * 4 + 2] = t.z; v[i * 4 + 3] = t.w;
#pragma unroll
    for (int j = 0; j < 4; ++j) mx = fmaxf(mx, fabsf(v[i * 4 + j]));
  }
#pragma unroll
  for (int m = 1; m < 64; m <<= 1) mx = fmaxf(mx, __shfl_xor(mx, m));
  const float scale = mx > 0.f ? 127.f / mx : 0.f;
  u32 pk[4];
#pragma unroll
  for (int i = 0; i < 4; ++i) {
    u32 b0 = (u32)(__float2int_rn(v[i * 4 + 0] * scale) & 0xff);
    u32 b1 = (u32)(__float2int_rn(v[i * 4 + 1] * scale) & 0xff);
    u32 b2 = (u32)(__float2int_rn(v[i * 4 + 2] * scale) & 0xff);
    u32 b3 = (u32)(__float2int_rn(v[i * 4 + 3] * scale) & 0xff);
    pk[i] = b0 | (b1 << 8) | (b2 << 16) | (b3 << 24);
  }
  *(uint4*)(out + (size_t)row * 1024 + lane * 16) = make_uint4(pk[0], pk[1], pk[2], pk[3]);
  if (lane == 0) sc[row] = mx > 0.f ? mx / 127.f : 0.f;
}

// ---------------------------------------------------------------------------
// per-row signed-i8 quantization of a bf16 matrix (wave/row) — attn output
__global__ __launch_bounds__(256) void quant_i8(const u16* __restrict__ in,
                                                u8* __restrict__ out,
                                                float* __restrict__ sc) {
  const int row  = blockIdx.x * 4 + (threadIdx.x >> 6);
  const int lane = threadIdx.x & 63;
  const u16* p = in + (size_t)row * 1024 + lane * 16;
  float v[16];
  float mx = 0.f;
#pragma unroll
  for (int i = 0; i < 2; ++i) {
    bf16x8 t = *(const bf16x8*)(p + i * 8);
#pragma unroll
    for (int j = 0; j < 8; ++j) {
      float f = bf2f((u16)t[j]);
      v[i * 8 + j] = f;
      mx = fmaxf(mx, fabsf(f));
    }
  }
#pragma unroll
  for (int m = 1; m < 64; m <<= 1) mx = fmaxf(mx, __shfl_xor(mx, m));
  const float scale = mx > 0.f ? 127.f / mx : 0.f;
  u32 pk[4];
#pragma unroll
  for (int i = 0; i < 4; ++i) {
    u32 b0 = (u32)(__float2int_rn(v[i * 4 + 0] * scale) & 0xff);
    u32 b1 = (u32)(__float2int_rn(v[i * 4 + 1] * scale) & 0xff);
    u32 b2 = (u32)(__float2int_rn(v[i * 4 + 2] * scale) & 0xff);
    u32 b3 = (u32)(__float2int_rn(v[i * 4 + 3] * scale) & 0xff);
    pk[i] = b0 | (b1 << 8) | (b2 << 16) | (b3 << 24);
  }
  *(uint4*)(out + (size_t)row * 1024 + lane * 16) = make_uint4(pk[0], pk[1], pk[2], pk[3]);
  if (lane == 0) sc[row] = mx > 0.f ? mx / 127.f : 0.f;
}

// ---------------------------------------------------------------------------
// h row (1024) per wave: h = relu(x*W+b), per-row max, quantize to i8 [0,127]
__global__ __launch_bounds__(256) void hgen_i8(const float* __restrict__ x,
                                               const float* __restrict__ W,
                                               const float* __restrict__ bias,
                                               u8* __restrict__ h, float* __restrict__ hsc,
                                               int F, int logF, int b0, int xstride) {
  const int row  = blockIdx.x * 4 + (threadIdx.x >> 6);
  const int lane = threadIdx.x & 63;
  const int f = row & (F - 1);
  const int b = b0 + (row >> logF);
  const float xv = x[(size_t)b * xstride + f];
  const float4* wp = (const float4*)(W + (size_t)f * 1024 + lane * 16);
  const float4* bp = (const float4*)(bias + (size_t)f * 1024 + lane * 16);
  float hv[16];
  float mx = 0.f;
#pragma unroll
  for (int i = 0; i < 4; ++i) {
    float4 wv = wp[i];
    float4 bv = bp[i];
    hv[i * 4 + 0] = fmaxf(xv * wv.x + bv.x, 0.f);
    hv[i * 4 + 1] = fmaxf(xv * wv.y + bv.y, 0.f);
    hv[i * 4 + 2] = fmaxf(xv * wv.z + bv.z, 0.f);
    hv[i * 4 + 3] = fmaxf(xv * wv.w + bv.w, 0.f);
#pragma unroll
    for (int j = 0; j < 4; ++j) mx = fmaxf(mx, hv[i * 4 + j]);
  }
#pragma unroll
  for (int m = 1; m < 64; m <<= 1) mx = fmaxf(mx, __shfl_xor(mx, m));
  const float scale = mx > 0.f ? 127.f / mx : 0.f;
  u32 pk[4];
#pragma unroll
  for (int i = 0; i < 4; ++i) {
    u32 q0 = (u32)__float2int_rn(hv[i * 4 + 0] * scale);
    u32 q1 = (u32)__float2int_rn(hv[i * 4 + 1] * scale);
    u32 q2 = (u32)__float2int_rn(hv[i * 4 + 2] * scale);
    u32 q3 = (u32)__float2int_rn(hv[i * 4 + 3] * scale);
    pk[i] = q0 | (q1 << 8) | (q2 << 16) | (q3 << 24);
  }
  *(uint4*)(h + (size_t)row * 1024 + lane * 16) = make_uint4(pk[0], pk[1], pk[2], pk[3]);
  if (lane == 0) hsc[row] = mx > 0.f ? mx / 127.f : 0.f;
}

// ---------------------------------------------------------------------------
// i8 GEMM: C(MxN,bf16) = sA[m]*sB[n]*(qA . qB^T) + bias(N)
// 256x128 tile, BK=64 i8, 8 waves 4Mx2N, triple-buffered, counted vmcnt(3).
// STATS: atomically accumulate per-row (sum, sumsq) partials into stats[row]
// (LayerNorm pre-pass fused into the epilogue).
template <bool STATS>
__global__ __launch_bounds__(512, 4) void gemm_i8(const u8* __restrict__ A,
                                                  const u8* __restrict__ B,
                                                  const float* __restrict__ sAsc,
                                                  const float* __restrict__ sBsc,
                                                  const float* __restrict__ bias,
                                                  u16* __restrict__ C,
                                                  float2* __restrict__ stats,
                                                  int M, int N, int K) {
  __shared__ u8 sA[3][256 * 64];
  __shared__ u8 sB[3][128 * 64];
  const int tid  = threadIdx.x;
  const int lane = tid & 63;
  const int w    = tid >> 6;
  const int wm   = w >> 1;
  const int wn   = w & 1;

  const int nwg = gridDim.x * gridDim.y;
  const int wg  = blockIdx.y * gridDim.x + blockIdx.x;
  const int swz = xcd_swz(wg, nwg);
  const int n0 = (swz % gridDim.x) * 128;
  const int m0 = (swz / gridDim.x) * 256;

  i32x4 acc[4][4] = {};

  const int r_in  = lane >> 2;
  const int s_src = (lane & 3) ^ ((lane >> 3) & 3);

  auto stage = [&](int kt, int b) {
    const int k0 = kt << 6;
    gload16(A + (size_t)(m0 + w * 16 + r_in) * K + k0 + s_src * 16, &sA[b][w * 1024]);
    gload16(A + (size_t)(m0 + (w + 8) * 16 + r_in) * K + k0 + s_src * 16, &sA[b][(w + 8) * 1024]);
    gload16(B + (size_t)(n0 + w * 16 + r_in) * K + k0 + s_src * 16, &sB[b][w * 1024]);
  };

  const int NT = K >> 6;
  stage(0, 0);
  stage(1, 1);
  asm volatile("s_waitcnt vmcnt(3)" ::: "memory");
  __builtin_amdgcn_s_barrier();

  int cur = 0, nx = 2;
  for (int t = 0; t < NT; ++t) {
    const bool more = (t + 2 < NT);
    if (more) stage(t + 2, nx);

    i32x4 af[4], bg[4];
    const int g = lane >> 4;
#pragma unroll
    for (int mf = 0; mf < 4; ++mf) {
      int ra = wm * 64 + mf * 16 + (lane & 15);
      af[mf] = *(const i32x4*)(&sA[cur][ra * 64 + ((g ^ ((ra >> 1) & 3)) * 16)]);
    }
#pragma unroll
    for (int nf = 0; nf < 4; ++nf) {
      int rb = wn * 64 + nf * 16 + (lane & 15);
      bg[nf] = *(const i32x4*)(&sB[cur][rb * 64 + ((g ^ ((rb >> 1) & 3)) * 16)]);
    }
    asm volatile("s_waitcnt lgkmcnt(0)" ::: "memory");
    __builtin_amdgcn_sched_barrier(0);
    __builtin_amdgcn_s_setprio(1);
#pragma unroll
    for (int mf = 0; mf < 4; ++mf)
#pragma unroll
      for (int nf = 0; nf < 4; ++nf)
        mfma_i8(acc[mf][nf], af[mf], bg[nf]);
    __builtin_amdgcn_s_setprio(0);
    if (more) asm volatile("s_waitcnt vmcnt(3)" ::: "memory");
    else      asm volatile("s_waitcnt vmcnt(0)" ::: "memory");
    __builtin_amdgcn_s_barrier();
    cur = (cur == 2) ? 0 : cur + 1;
    nx  = (nx  == 2) ? 0 : nx  + 1;
  }

  // epilogue: D layout col = lane&15, row = (lane>>4)*4 + reg; de-scale rank-1
  float sb4[4], bs4[4];
#pragma unroll
  for (int nf = 0; nf < 4; ++nf) {
    int cl = n0 + wn * 64 + nf * 16 + (lane & 15);
    sb4[nf] = sBsc[cl];
    bs4[nf] = bias[cl];
  }
#pragma unroll
  for (int mf = 0; mf < 4; ++mf) {
    int r0 = m0 + wm * 64 + mf * 16 + (lane >> 4) * 4;
    float4 sa4 = *(const float4*)(sAsc + r0);
    const float* sap = (const float*)&sa4;
#pragma unroll
    for (int reg = 0; reg < 4; ++reg) {
      float s = 0.f, s2 = 0.f;
#pragma unroll
      for (int nf = 0; nf < 4; ++nf) {
        int cl = n0 + wn * 64 + nf * 16 + (lane & 15);
        float v = (float)acc[mf][nf][reg] * (sap[reg] * sb4[nf]) + bs4[nf];
        C[(size_t)(r0 + reg) * N + cl] = f2bf(v);
        if (STATS) { s += v; s2 += v * v; }
      }
      if (STATS) {
#pragma unroll
        for (int m = 1; m < 16; m <<= 1) { s += __shfl_xor(s, m); s2 += __shfl_xor(s2, m); }
        if ((lane & 15) == 0) {
          atomicAdd(&stats[r0 + reg].x, s);
          atomicAdd(&stats[r0 + reg].y, s2);
        }
      }
    }
  }
}

// finalize LN stats: (sum, sumsq) -> (mu, rsqrt(var+eps))
__global__ __launch_bounds__(256) void ln_fin(float2* __restrict__ stats, int n) {
  int i = blockIdx.x * 256 + threadIdx.x;
  if (i >= n) return;
  float2 s = stats[i];
  float mu  = s.x * (1.f / 1024.f);
  float var = s.y * (1.f / 1024.f) - mu * mu;
  stats[i] = make_float2(mu, rsqrtf(var + 1e-5f));
}

// ---------------------------------------------------------------------------
// Fused attention, QBLK = F (one block per (head, batch)).
// nw = blockDim.x/64 waves (drug: 16, target: 8); wave w owns q-rows w*16..+15,
// Q in registers; K/V staged ONCE per (head,batch) — no duplicate staging.
// Softmax in exp2 units (log2e folded into Q scale) + defer-max (T13, THR=8).
__global__ __launch_bounds__(1024) void attn(const u16* __restrict__ qkv,
                                             u16* __restrict__ o_out, int F) {
  __shared__ u16 k_lds[64 * 136];
  __shared__ u16 vT[128 * 72];        // [128 d][64+8 kpos], col-swizzled
  __shared__ u16 p_lds[16 * 16 * 72]; // per-wave [16 qrow][64+8 kpos]

  const int tid  = threadIdx.x;
  const int lane = tid & 63;
  const int w    = tid >> 6;
  const int nt   = blockDim.x;

  const int head = blockIdx.x & 7;
  const int bc   = blockIdx.x >> 3;

  const size_t rowbase = (size_t)bc * F * 3072;
  const float scale = 0.12751744865678818f;   // log2(e)/sqrt(128)

  const int qr = lane & 15;
  const int g4 = lane >> 4;

  // Q fragments in registers: row (w*16 + qr), 16B slices kk*32+8*g4
  bf16x8 qreg[4];
  {
    const u16* qsrc = qkv + rowbase + (size_t)(w * 16 + qr) * 3072 + head * 128;
#pragma unroll
    for (int kk = 0; kk < 4; ++kk) {
      bf16x8 v = *(const bf16x8*)(qsrc + kk * 32 + 8 * g4);
#pragma unroll
      for (int j = 0; j < 8; ++j) v[j] = (short)f2bf(bf2f((u16)v[j]) * scale);
      qreg[kk] = v;
    }
  }

  f32x4 o_acc[8] = {};
  float m_run = -INFINITY, l_run = 0.f;

  const int nkb = F >> 6;
  for (int kb = 0; kb < nkb; ++kb) {
    __syncthreads();   // prev compute done with k_lds/vT
    const u16* ksrc = qkv + rowbase + (size_t)(kb * 64) * 3072 + 1024 + head * 128;
    const u16* vsrc = ksrc + 1024;
    for (int it = tid; it < 1024; it += nt) {
      int r = it >> 4, s = it & 15;
      *(bf16x8*)(k_lds + r * 136 + s * 8) = *(const bf16x8*)(ksrc + (size_t)r * 3072 + s * 8);
    }
    for (int it = tid; it < 512; it += nt) {
      int g2 = it >> 4, s = it & 15;
      const u16* v0 = vsrc + (size_t)(2 * g2) * 3072 + s * 8;
      bf16x8 a = *(const bf16x8*)(v0);
      bf16x8 b = *(const bf16x8*)(v0 + 3072);
      int rs0 = (2 * g2) ^ ((s & 7) << 3);
      int d0  = s * 8;
#pragma unroll
      for (int j = 0; j < 8; ++j) {
        u32 pk = (u32)(u16)a[j] | ((u32)(u16)b[j] << 16);
        *(u32*)(vT + (d0 + j) * 72 + rs0) = pk;
      }
    }
    __syncthreads();

    // S^T (64 kpos x 16 qrows): A = k rows, B = q^T (registers)
    f32x4 sa[4] = {};
#pragma unroll
    for (int kk = 0; kk < 4; ++kk) {
#pragma unroll
      for (int f = 0; f < 4; ++f) {
        bf16x8 ak = *(const bf16x8*)(k_lds + (f * 16 + qr) * 136 + kk * 32 + 8 * g4);
        sa[f] = __builtin_amdgcn_mfma_f32_16x16x32_bf16(ak, qreg[kk], sa[f], 0, 0, 0);
      }
    }

    float tmax = -INFINITY;
#pragma unroll
    for (int f = 0; f < 4; ++f)
#pragma unroll
      for (int rr = 0; rr < 4; ++rr) tmax = fmaxf(tmax, sa[f][rr]);
    tmax = fmaxf(tmax, __shfl_xor(tmax, 16));
    tmax = fmaxf(tmax, __shfl_xor(tmax, 32));

    // defer-max (T13): skip rescale while the running max is still adequate
    const bool ns = !__all(tmax - m_run <= 8.f);
    float mnew = m_run, alpha = 1.f;
    if (ns) { mnew = fmaxf(m_run, tmax); alpha = exp2f(m_run - mnew); }

    float psum = 0.f;
#pragma unroll
    for (int f = 0; f < 4; ++f) {
      u16 pp[4];
#pragma unroll
      for (int rr = 0; rr < 4; ++rr) {
        float p = exp2f(sa[f][rr] - mnew);
        psum += p;
        pp[rr] = f2bf(p);
      }
      uint2 u;
      u.x = (u32)pp[0] | ((u32)pp[1] << 16);
      u.y = (u32)pp[2] | ((u32)pp[3] << 16);
      *(uint2*)(p_lds + w * 1152 + qr * 72 + f * 16 + g4 * 4) = u;
    }
    psum += __shfl_xor(psum, 16);
    psum += __shfl_xor(psum, 32);
    l_run = l_run * alpha + psum;
    m_run = mnew;

    if (ns) {
#pragma unroll
      for (int rr = 0; rr < 4; ++rr) {
        float ar = __shfl(alpha, g4 * 4 + rr);
#pragma unroll
        for (int g = 0; g < 8; ++g) o_acc[g][rr] *= ar;
      }
    }

#pragma unroll
    for (int kk2 = 0; kk2 < 2; ++kk2) {
      bf16x8 pa = *(const bf16x8*)(p_lds + w * 1152 + qr * 72 + kk2 * 32 + 8 * g4);
#pragma unroll
      for (int g = 0; g < 8; ++g) {
        int swv = ((g * 2 + (qr >> 3)) & 7) << 3;
        bf16x8 vb = *(const bf16x8*)(vT + (g * 16 + qr) * 72 + ((kk2 * 32 + 8 * g4) ^ swv));
        o_acc[g] = __builtin_amdgcn_mfma_f32_16x16x32_bf16(pa, vb, o_acc[g], 0, 0, 0);
      }
    }
  }

  float linv = 1.f / l_run;
#pragma unroll
  for (int rr = 0; rr < 4; ++rr) {
    float lr = __shfl(linv, g4 * 4 + rr);
    size_t row = (size_t)bc * F + w * 16 + g4 * 4 + rr;
#pragma unroll
    for (int g = 0; g < 8; ++g)
      o_out[row * 1024 + head * 128 + g * 16 + qr] = f2bf(o_acc[g][rr] * lr);
  }
}

// ---------------------------------------------------------------------------
__global__ __launch_bounds__(256) void ln_accum(const u16* __restrict__ proj,
                                                const float2* __restrict__ stats,
                                                const float* __restrict__ g,
                                                const float* __restrict__ beta,
                                                float* __restrict__ dp, int F, int b0) {
  int d  = blockIdx.x * 256 + threadIdx.x;
  int bc = blockIdx.z;
  int f0 = blockIdx.y * 64;
  const u16* base = proj + ((size_t)(bc * F + f0)) * 1024 + d;
  const float2* st = stats + bc * F + f0;
  float acc = 0.f;
  for (int f = 0; f < 64; ++f) {
    float2 s = st[f];
    acc += (bf2f(base[(size_t)f * 1024]) - s.x) * s.y;
  }
  acc = acc * g[d] + 64.f * beta[d];
  atomicAdd(&dp[(size_t)(b0 + bc) * 1024 + d], acc);
}

// ---------------------------------------------------------------------------
__global__ __launch_bounds__(256) void cosine_sig(const float* __restrict__ dp,
                                                  const float* __restrict__ tp,
                                                  float* __restrict__ out) {
  __shared__ float red[3][4];
  int b = blockIdx.x;
  int tid = threadIdx.x, lane = tid & 63, w = tid >> 6;
  float dot = 0.f, n1 = 0.f, n2 = 0.f;
  for (int i = tid; i < 1024; i += 256) {
    float a = dp[(size_t)b * 1024 + i], c = tp[(size_t)b * 1024 + i];
    dot += a * c; n1 += a * a; n2 += c * c;
  }
#pragma unroll
  for (int m = 1; m < 64; m <<= 1) {
    dot += __shfl_xor(dot, m); n1 += __shfl_xor(n1, m); n2 += __shfl_xor(n2, m);
  }
  if (lane == 0) { red[0][w] = dot; red[1][w] = n1; red[2][w] = n2; }
  __syncthreads();
  if (tid == 0) {
    dot = red[0][0] + red[0][1] + red[0][2] + red[0][3];
    n1  = red[1][0] + red[1][1] + red[1][2] + red[1][3];
    n2  = red[2][0] + red[2][1] + red[2][2] + red[2][3];
    float denom = fmaxf(sqrtf(n1) * sqrtf(n2), 1e-8f);
    out[b] = 1.f / (1.f + __expf(-dot / denom));
  }
}

// ---------------------------------------------------------------------------
extern "C" void kernel_launch(void* const* d_in, const int* in_sizes, int n_in,
                              void* d_out, int out_size, void* d_ws, size_t ws_size,
                              hipStream_t stream) {
  const float* drug   = (const float*)d_in[0];
  const float* target = (const float*)d_in[1];

  char* p = (char*)d_ws;
  auto alloc = [&](size_t bytes) -> char* {
    char* r = p; p += (bytes + 255) & ~(size_t)255; return r;
  };

  u8*    w8_d    = (u8*)alloc((size_t)3072 * 1024);
  float* wsc_d   = (float*)alloc((size_t)3072 * 4);
  u8*    w8_t    = (u8*)alloc((size_t)3072 * 1024);
  float* wsc_t   = (float*)alloc((size_t)3072 * 4);
  u8*    w8o_d   = (u8*)alloc((size_t)1024 * 1024);
  float* wsco_d  = (float*)alloc((size_t)1024 * 4);
  u8*    w8o_t   = (u8*)alloc((size_t)1024 * 1024);
  float* wsco_t  = (float*)alloc((size_t)1024 * 4);
  float* dp      = (float*)alloc((size_t)2 * 128 * 1024 * 4);
  float* tp      = dp + 128 * 1024;

  size_t fixed = (size_t)(p - (char*)d_ws);
  size_t per = (size_t)256 * 1024               /* h_i8 (reused as o_i8) */
             + (size_t)256 * 4                  /* hsc (reused as osc) */
             + (size_t)256 * 3072 * 2           /* qkv */
             + (size_t)256 * 1024 * 2 * 2       /* obuf + proj */
             + (size_t)256 * 8 + 4096;          /* stats + slack */
  int Bc = 8;
  if      (fixed + 128 * per <= ws_size) Bc = 128;
  else if (fixed +  64 * per <= ws_size) Bc = 64;
  else if (fixed +  32 * per <= ws_size) Bc = 32;
  else if (fixed +  16 * per <= ws_size) Bc = 16;

  u8*    h8     = (u8*)alloc((size_t)Bc * 256 * 1024);   // also o_i8 after qkv
  float* hsc    = (float*)alloc((size_t)Bc * 256 * 4);   // also osc
  u16*   qkvbuf = (u16*)alloc((size_t)Bc * 256 * 3072 * 2);
  u16*   obuf   = (u16*)alloc((size_t)Bc * 256 * 1024 * 2);
  u16*   projbuf= (u16*)alloc((size_t)Bc * 256 * 1024 * 2);
  float2* statsb = (float2*)alloc((size_t)Bc * 256 * 8);

  cvt_w_i8<<<768, 256, 0, stream>>>((const float*)d_in[4],  w8_d, wsc_d);
  cvt_w_i8<<<768, 256, 0, stream>>>((const float*)d_in[12], w8_t, wsc_t);
  cvt_w_i8<<<256, 256, 0, stream>>>((const float*)d_in[6],  w8o_d, wsco_d);
  cvt_w_i8<<<256, 256, 0, stream>>>((const float*)d_in[14], w8o_t, wsco_t);
  hipMemsetAsync(dp, 0, (size_t)2 * 128 * 1024 * 4, stream);

  for (int br = 0; br < 2; ++br) {
    const int F = br ? 128 : 256, logF = br ? 7 : 8, xstride = br ? 1024 : 2048;
    const float* x    = br ? target : drug;
    const float* W    = (const float*)d_in[br ? 10 : 2];
    const float* Wb   = (const float*)d_in[br ? 11 : 3];
    u8*          w8   = br ? w8_t : w8_d;
    float*       wsc  = br ? wsc_t : wsc_d;
    const float* inb  = (const float*)d_in[br ? 13 : 5];
    u8*          w8o  = br ? w8o_t : w8o_d;
    float*       wsco = br ? wsco_t : wsco_d;
    const float* outb = (const float*)d_in[br ? 15 : 7];
    const float* gg   = (const float*)d_in[br ? 16 : 8];
    const float* bb   = (const float*)d_in[br ? 17 : 9];
    float*       accp = br ? tp : dp;

    const int nb = (br ? (2 * Bc > 128 ? 128 : 2 * Bc) : (Bc > 128 ? 128 : Bc));

    for (int b0 = 0; b0 < 128; b0 += nb) {
      const int Mr = nb * F;
      hgen_i8<<<Mr / 4, 256, 0, stream>>>(x, W, Wb, h8, hsc, F, logF, b0, xstride);
      gemm_i8<false><<<dim3(3072 / 128, Mr / 256), 512, 0, stream>>>(
          h8, w8, hsc, wsc, inb, qkvbuf, nullptr, Mr, 3072, 1024);
      attn<<<8 * nb, 64 * (F / 16), 0, stream>>>(qkvbuf, obuf, F);
      quant_i8<<<Mr / 4, 256, 0, stream>>>(obuf, h8, hsc);   // h8/hsc reused as o8/osc
      hipMemsetAsync(statsb, 0, (size_t)Mr * 8, stream);
      gemm_i8<true><<<dim3(1024 / 128, Mr / 256), 512, 0, stream>>>(
          h8, w8o, hsc, wsco, outb, projbuf, statsb, Mr, 1024, 1024);
      ln_fin<<<(Mr + 255) / 256, 256, 0, stream>>>(statsb, Mr);
      ln_accum<<<dim3(4, F / 64, nb), 256, 0, stream>>>(projbuf, statsb, gg, bb, accp, F, b0);
    }
  }
  cosine_sig<<<128, 256, 0, stream>>>(dp, tp, (float*)d_out);
}